// Round 17
// baseline (389.747 us; speedup 1.0000x reference)
//
#include <hip/hip_runtime.h>
#include <math.h>
#include <stdint.h>

#define N0 100000
#define N1 25000
#define N2 6250
#define FD 128

typedef unsigned short u16;
typedef unsigned int u32;
typedef short bf16x8 __attribute__((ext_vector_type(8)));
typedef float f32x4 __attribute__((ext_vector_type(4)));

static inline int ceildiv(int a, int b){ return (a + b - 1)/b; }

__device__ __forceinline__ u16 f2bf(float f){
  u32 u = __float_as_uint(f);
  u += 0x7fffu + ((u >> 16) & 1u);
  return (u16)(u >> 16);
}
__device__ __forceinline__ float bf2f(u16 h){
  return __uint_as_float(((u32)h) << 16);
}
__device__ __forceinline__ float blo(u32 u){ return __uint_as_float(u << 16); }
__device__ __forceinline__ float bhi(u32 u){ return __uint_as_float(u & 0xffff0000u); }
__device__ __forceinline__ u32 pk2(float a, float b){ return (u32)f2bf(a) | ((u32)f2bf(b) << 16); }

// ================= bucket metadata: 10 jobs =================
struct BMeta {
  const int* key[10];
  const int* src[7];
  int* rowp[7]; int* csr[7];
  float* rsout[3];
  int n[10], E[10], B[10], r[10];
  int cap[10];
  int ebase[10];
  int boff[11];
  int pblk[11];
};

__device__ __forceinline__ int capbase(const BMeta& m, int bb){
  int j = 0;
  #pragma unroll
  for (int t = 1; t < 10; ++t) if (bb >= m.boff[t]) j = t;
  return m.ebase[j] + (bb - m.boff[j]) * m.cap[j];
}

// ================= FMA GEMM (small cases) =================
__device__ __forceinline__ void mm_inner(const float* Al, const float* Wl, int r0, int c0, float acc[4][4]){
  #pragma unroll
  for (int kq = 0; kq < 8; ++kq) {
    int k0 = kq*4;
    float4 a[4], w[4];
    #pragma unroll
    for (int i=0;i<4;++i) a[i] = *(const float4*)&Al[(r0+i)*32 + k0];
    #pragma unroll
    for (int kk=0;kk<4;++kk) w[kk] = *(const float4*)&Wl[(k0+kk)*128 + c0];
    #pragma unroll
    for (int i=0;i<4;++i){
      acc[i][0] = fmaf(a[i].x,w[0].x, fmaf(a[i].y,w[1].x, fmaf(a[i].z,w[2].x, fmaf(a[i].w,w[3].x, acc[i][0]))));
      acc[i][1] = fmaf(a[i].x,w[0].y, fmaf(a[i].y,w[1].y, fmaf(a[i].z,w[2].y, fmaf(a[i].w,w[3].y, acc[i][1]))));
      acc[i][2] = fmaf(a[i].x,w[0].z, fmaf(a[i].y,w[1].z, fmaf(a[i].z,w[2].z, fmaf(a[i].w,w[3].z, acc[i][2]))));
      acc[i][3] = fmaf(a[i].x,w[0].w, fmaf(a[i].y,w[1].w, fmaf(a[i].z,w[2].w, fmaf(a[i].w,w[3].w, acc[i][3]))));
    }
  }
}

template<int SCORE, int AB16>
__device__ __forceinline__ void dev_gemm(float* Wl, float* Al, int bid,
    const void* __restrict__ Ap,
    const float* __restrict__ W, const float* __restrict__ bias,
    const float* __restrict__ kvec, float* __restrict__ sOut,
    u16* __restrict__ out, int n)
{
  const int tid = threadIdx.x;
  const int row0 = bid * 32;
  const int c0 = (tid & 31) * 4, r0 = (tid >> 5) * 4;
  const int r = tid >> 3, fc = tid & 7;
  const int gr_s = row0 + r;
  float acc[4][4] = {};
  float sacc = 0.f;
  const float4* W4 = (const float4*)W;
  for (int kp = 0; kp < 4; ++kp) {
    float4* Wl4 = (float4*)Wl;
    #pragma unroll
    for (int i = 0; i < 4; ++i) Wl4[tid + 256*i] = W4[kp*1024 + tid + 256*i];
    {
      float4 v = make_float4(0.f,0.f,0.f,0.f);
      if (gr_s < n){
        if (AB16){
          ushort4 h = ((const ushort4*)Ap)[(size_t)gr_s*32 + kp*8 + fc];
          v = make_float4(bf2f(h.x), bf2f(h.y), bf2f(h.z), bf2f(h.w));
        } else {
          v = ((const float4*)Ap)[(size_t)gr_s*32 + kp*8 + fc];
        }
      }
      ((float4*)Al)[tid] = v;
      if (SCORE){
        float4 kv = *(const float4*)&kvec[kp*32 + fc*4];
        sacc += v.x*kv.x + v.y*kv.y + v.z*kv.z + v.w*kv.w;
      }
    }
    __syncthreads();
    mm_inner(Al, Wl, r0, c0, acc);
    __syncthreads();
  }
  if (SCORE){
    sacc += __shfl_xor(sacc, 1);
    sacc += __shfl_xor(sacc, 2);
    sacc += __shfl_xor(sacc, 4);
    if (fc == 0 && gr_s < n) sOut[gr_s] = expf(sacc + kvec[128]);
  }
  float4 bv = make_float4(0.f,0.f,0.f,0.f);
  if (bias) bv = *(const float4*)&bias[c0];
  #pragma unroll
  for (int i=0;i<4;++i){
    int gr = row0 + r0 + i;
    if (gr < n){
      ushort4 o;
      o.x = f2bf(acc[i][0]+bv.x); o.y = f2bf(acc[i][1]+bv.y);
      o.z = f2bf(acc[i][2]+bv.z); o.w = f2bf(acc[i][3]+bv.w);
      *(ushort4*)&out[(size_t)gr*FD + c0] = o;
    }
  }
}

// ================= MFMA GEMMs (LDS-free) =================
__device__ __forceinline__ void dev_dual_mfma(int bid,
    const u16* __restrict__ A, const u16* __restrict__ WvT, const u16* __restrict__ WgT,
    const float* __restrict__ vb, const float* __restrict__ kvec, float* __restrict__ sOut,
    u16* __restrict__ Vout, u16* __restrict__ Yout, int n)
{
  const int tid = threadIdx.x;
  const int wid = tid >> 6, lane = tid & 63;
  const int l15 = lane & 15, lg = lane >> 4;
  const int rt = wid & 1;
  const int cbase = (wid >> 1) * 64;
  const int row0 = bid * 32;
  const int arow = row0 + rt*16 + l15;
  const int arowc = min(arow, n-1);
  f32x4 accV[4] = {{0.f,0.f,0.f,0.f},{0.f,0.f,0.f,0.f},{0.f,0.f,0.f,0.f},{0.f,0.f,0.f,0.f}};
  f32x4 accY[4] = {{0.f,0.f,0.f,0.f},{0.f,0.f,0.f,0.f},{0.f,0.f,0.f,0.f},{0.f,0.f,0.f,0.f}};
  float sacc = 0.f;
  #pragma unroll
  for (int ks = 0; ks < 4; ++ks){
    const int ko = ks*32 + lg*8;
    bf16x8 a = *(const bf16x8*)(A + (size_t)arowc*FD + ko);
    if (wid < 2){
      float4 k0 = *(const float4*)(kvec + ko);
      float4 k1 = *(const float4*)(kvec + ko + 4);
      sacc += bf2f((u16)a[0])*k0.x + bf2f((u16)a[1])*k0.y + bf2f((u16)a[2])*k0.z + bf2f((u16)a[3])*k0.w
            + bf2f((u16)a[4])*k1.x + bf2f((u16)a[5])*k1.y + bf2f((u16)a[6])*k1.z + bf2f((u16)a[7])*k1.w;
    }
    #pragma unroll
    for (int ct = 0; ct < 4; ++ct){
      const int col = cbase + ct*16 + l15;
      bf16x8 bv = *(const bf16x8*)(WvT + (size_t)col*FD + ko);
      bf16x8 bg = *(const bf16x8*)(WgT + (size_t)col*FD + ko);
      accV[ct] = __builtin_amdgcn_mfma_f32_16x16x32_bf16(a, bv, accV[ct], 0, 0, 0);
      accY[ct] = __builtin_amdgcn_mfma_f32_16x16x32_bf16(a, bg, accY[ct], 0, 0, 0);
    }
  }
  if (wid < 2){
    sacc += __shfl_xor(sacc, 16);
    sacc += __shfl_xor(sacc, 32);
    if (lane < 16 && arow < n) sOut[arow] = expf(sacc + kvec[128]);
  }
  #pragma unroll
  for (int ct = 0; ct < 4; ++ct){
    const int col = cbase + ct*16 + l15;
    const float bvv = vb[col];
    #pragma unroll
    for (int i = 0; i < 4; ++i){
      int gr = row0 + rt*16 + lg*4 + i;
      if (gr < n){
        Vout[(size_t)gr*FD + col] = f2bf(accV[ct][i] + bvv);
        Yout[(size_t)gr*FD + col] = f2bf(accY[ct][i]);
      }
    }
  }
}

template<int AF32, int SCORE>
__device__ __forceinline__ void dev_single_mfma(int bid,
    const void* __restrict__ Ap, const u16* __restrict__ WT,
    const float* __restrict__ bias,
    const float* __restrict__ kvec, float* __restrict__ sOut,
    u16* __restrict__ out, int n)
{
  const int tid = threadIdx.x;
  const int wid = tid >> 6, lane = tid & 63;
  const int l15 = lane & 15, lg = lane >> 4;
  const int rt = wid & 1;
  const int cbase = (wid >> 1) * 64;
  const int row0 = bid * 32;
  const int arow = row0 + rt*16 + l15;
  const int arowc = min(arow, n-1);
  f32x4 acc[4] = {{0.f,0.f,0.f,0.f},{0.f,0.f,0.f,0.f},{0.f,0.f,0.f,0.f},{0.f,0.f,0.f,0.f}};
  float sacc = 0.f;
  #pragma unroll
  for (int ks = 0; ks < 4; ++ks){
    const int ko = ks*32 + lg*8;
    bf16x8 a;
    if (AF32){
      const float* Af = (const float*)Ap + (size_t)arowc*FD + ko;
      float4 f0 = *(const float4*)Af;
      float4 f1 = *(const float4*)(Af + 4);
      a[0]=(short)f2bf(f0.x); a[1]=(short)f2bf(f0.y); a[2]=(short)f2bf(f0.z); a[3]=(short)f2bf(f0.w);
      a[4]=(short)f2bf(f1.x); a[5]=(short)f2bf(f1.y); a[6]=(short)f2bf(f1.z); a[7]=(short)f2bf(f1.w);
      if (SCORE && wid < 2){
        float4 k0 = *(const float4*)(kvec + ko);
        float4 k1 = *(const float4*)(kvec + ko + 4);
        sacc += f0.x*k0.x + f0.y*k0.y + f0.z*k0.z + f0.w*k0.w
              + f1.x*k1.x + f1.y*k1.y + f1.z*k1.z + f1.w*k1.w;
      }
    } else {
      a = *(const bf16x8*)((const u16*)Ap + (size_t)arowc*FD + ko);
      if (SCORE && wid < 2){
        float4 k0 = *(const float4*)(kvec + ko);
        float4 k1 = *(const float4*)(kvec + ko + 4);
        sacc += bf2f((u16)a[0])*k0.x + bf2f((u16)a[1])*k0.y + bf2f((u16)a[2])*k0.z + bf2f((u16)a[3])*k0.w
              + bf2f((u16)a[4])*k1.x + bf2f((u16)a[5])*k1.y + bf2f((u16)a[6])*k1.z + bf2f((u16)a[7])*k1.w;
      }
    }
    #pragma unroll
    for (int ct = 0; ct < 4; ++ct){
      const int col = cbase + ct*16 + l15;
      bf16x8 bv = *(const bf16x8*)(WT + (size_t)col*FD + ko);
      acc[ct] = __builtin_amdgcn_mfma_f32_16x16x32_bf16(a, bv, acc[ct], 0, 0, 0);
    }
  }
  if (SCORE && wid < 2){
    sacc += __shfl_xor(sacc, 16);
    sacc += __shfl_xor(sacc, 32);
    if (lane < 16 && arow < n) sOut[arow] = expf(sacc + kvec[128]);
  }
  #pragma unroll
  for (int ct = 0; ct < 4; ++ct){
    const int col = cbase + ct*16 + l15;
    const float bvv = bias[col];
    #pragma unroll
    for (int i = 0; i < 4; ++i){
      int gr = row0 + rt*16 + lg*4 + i;
      if (gr < n) out[(size_t)gr*FD + col] = f2bf(acc[ct][i] + bvv);
    }
  }
}

// ================= bucket passes =================
__device__ __forceinline__ int job_of_blk(const BMeta& m, int bid){
  int j = 0;
  #pragma unroll
  for (int t = 1; t < 10; ++t) if (bid >= m.pblk[t]) j = t;
  return j;
}

// P2: 4-way sub-counters per (wave,bucket) to cut same-address LDS atomic
// serialization. sh: 4096 ints laid out sh[b + 64*(wid*4+sub)].
__device__ __forceinline__ void dev_p2(const BMeta& m, int bid, int* __restrict__ bktCur,
    u32* __restrict__ ebuf, u16* __restrict__ ebuf16, int* sh){
  int j = job_of_blk(m, bid);
  int lb = bid - m.pblk[j];
  const int* key = m.key[j];
  int E = m.E[j], r = m.r[j], B = m.B[j];
  int tid = threadIdx.x, wid = tid >> 6;
  for (int i = tid; i < 4096; i += 256) sh[i] = 0;
  __syncthreads();
  int base = lb*4096 + tid;
  int* myh = sh + 64*(wid*4 + (tid & 3));
  #pragma unroll
  for (int i = 0; i < 16; ++i){ int e = base + i*256; if (e < E) atomicAdd(&myh[key[e]/r], 1); }
  __syncthreads();
  if (tid < B){
    int tot = 0;
    #pragma unroll
    for (int a = 0; a < 16; ++a) tot += sh[tid + 64*a];
    int g = atomicAdd(&bktCur[m.boff[j] + tid], tot);
    #pragma unroll
    for (int a = 0; a < 16; ++a){ int c = sh[tid + 64*a]; sh[tid + 64*a] = g; g += c; }
  }
  __syncthreads();
  if (j < 7){
    const int* src = m.src[j];
    #pragma unroll
    for (int i = 0; i < 16; ++i){
      int e = base + i*256;
      if (e < E){
        int s = src[e], d = key[e];
        int b = d / r;
        int pos = atomicAdd(&myh[b], 1);
        ebuf[pos] = ((u32)(d - b*r) << 17) | (u32)s;
      }
    }
  } else {
    #pragma unroll
    for (int i = 0; i < 16; ++i){
      int e = base + i*256;
      if (e < E){
        int k = key[e];
        int b = k / r;
        int pos = atomicAdd(&myh[b], 1);
        ebuf16[pos] = (u16)(k - b*r);
      }
    }
  }
}

__device__ __forceinline__ void dev_p3(const BMeta& m, int bb,
    const int* __restrict__ bktCnt, const int* __restrict__ bktBase,
    const u32* __restrict__ ebuf, const u16* __restrict__ ebuf16, int* sh){
  int j = 0;
  #pragma unroll
  for (int t = 1; t < 10; ++t) if (bb >= m.boff[t]) j = t;
  int b = bb - m.boff[j];
  int n = m.n[j], r = m.r[j];
  int node0 = b*r;
  int rr = min(r, n - node0);
  int gbase = m.ebase[j] + b * m.cap[j];
  int cnt = bktCnt[bb];
  int tid = threadIdx.x;
  if (j >= 7){
    int* hist = sh;
    for (int i = tid; i < rr; i += 256) hist[i] = 0;
    __syncthreads();
    for (int e = tid; e < cnt; e += 256) atomicAdd(&hist[ebuf16[gbase + e]], 1);
    __syncthreads();
    float* rs = m.rsout[j-7];
    for (int i = tid; i < rr; i += 256) rs[node0 + i] = rsqrtf(fmaxf((float)hist[i], 1.f));
    return;
  }
  int B = m.B[j];
  int* rowp = m.rowp[j]; int* csr = m.csr[j];
  int lbase = bktBase[bb];
  int* hist = sh; int* aux = sh + 1568;
  for (int i = tid; i < rr; i += 256) hist[i] = 0;
  __syncthreads();
  for (int e = tid; e < cnt; e += 256){ u32 pk = ebuf[gbase + e]; atomicAdd(&hist[pk >> 17], 1); }
  __syncthreads();
  int ch = (rr + 255) >> 8;
  int i0 = tid*ch;
  int s = 0;
  for (int k = 0; k < ch; ++k){ int idx = i0 + k; if (idx < rr){ int t = hist[idx]; hist[idx] = s; s += t; } }
  aux[tid] = s; __syncthreads();
  for (int off = 1; off < 256; off <<= 1){
    int v = aux[tid]; int a = (tid >= off) ? aux[tid - off] : 0;
    __syncthreads();
    aux[tid] = v + a;
    __syncthreads();
  }
  int pre = (tid ? aux[tid-1] : 0) + lbase;
  for (int k = 0; k < ch; ++k){ int idx = i0 + k; if (idx < rr) hist[idx] += pre; }
  __syncthreads();
  for (int i = tid; i < rr; i += 256) rowp[node0 + i] = hist[i];
  if (b == B-1 && tid == 0) rowp[n] = lbase + cnt;
  __syncthreads();
  for (int e = tid; e < cnt; e += 256){
    u32 pk = ebuf[gbase + e];
    int pos = atomicAdd(&hist[pk >> 17], 1);
    csr[pos] = (int)(pk & 0x1FFFFu);
  }
}

// ================= 16-lane gathers, 4-deep pipelined =================
template<int OB16>
__device__ __forceinline__ void dev_attn_gather16(int bid,
    const int* __restrict__ csr, const int* __restrict__ rowp,
    const float* __restrict__ w, const u16* __restrict__ V,
    void* __restrict__ out, int n)
{
  int g = threadIdx.x >> 4, lane = threadIdx.x & 15;
  int row = bid*16 + g;
  if (row >= n) return;
  int st = rowp[row], en = rowp[row+1];
  float a0=0,a1=0,a2=0,a3=0,a4=0,a5=0,a6=0,a7=0;
  if (en > st){
    const uint4* V8 = (const uint4*)V;
    float den = 0.f;
    int e = st;
    for (; e + 4 <= en; e += 4){
      int s0=csr[e], s1=csr[e+1], s2=csr[e+2], s3=csr[e+3];
      float x0=w[s0], x1=w[s1], x2=w[s2], x3=w[s3];
      uint4 v0=V8[(size_t)s0*16+lane], v1=V8[(size_t)s1*16+lane];
      uint4 v2=V8[(size_t)s2*16+lane], v3=V8[(size_t)s3*16+lane];
      den += x0+x1+x2+x3;
      a0=fmaf(x0,blo(v0.x),a0); a1=fmaf(x0,bhi(v0.x),a1); a2=fmaf(x0,blo(v0.y),a2); a3=fmaf(x0,bhi(v0.y),a3);
      a4=fmaf(x0,blo(v0.z),a4); a5=fmaf(x0,bhi(v0.z),a5); a6=fmaf(x0,blo(v0.w),a6); a7=fmaf(x0,bhi(v0.w),a7);
      a0=fmaf(x1,blo(v1.x),a0); a1=fmaf(x1,bhi(v1.x),a1); a2=fmaf(x1,blo(v1.y),a2); a3=fmaf(x1,bhi(v1.y),a3);
      a4=fmaf(x1,blo(v1.z),a4); a5=fmaf(x1,bhi(v1.z),a5); a6=fmaf(x1,blo(v1.w),a6); a7=fmaf(x1,bhi(v1.w),a7);
      a0=fmaf(x2,blo(v2.x),a0); a1=fmaf(x2,bhi(v2.x),a1); a2=fmaf(x2,blo(v2.y),a2); a3=fmaf(x2,bhi(v2.y),a3);
      a4=fmaf(x2,blo(v2.z),a4); a5=fmaf(x2,bhi(v2.z),a5); a6=fmaf(x2,blo(v2.w),a6); a7=fmaf(x2,bhi(v2.w),a7);
      a0=fmaf(x3,blo(v3.x),a0); a1=fmaf(x3,bhi(v3.x),a1); a2=fmaf(x3,blo(v3.y),a2); a3=fmaf(x3,bhi(v3.y),a3);
      a4=fmaf(x3,blo(v3.z),a4); a5=fmaf(x3,bhi(v3.z),a5); a6=fmaf(x3,blo(v3.w),a6); a7=fmaf(x3,bhi(v3.w),a7);
    }
    for (; e < en; ++e){
      int sn = csr[e];
      float x = w[sn];
      uint4 v = V8[(size_t)sn*16 + lane];
      den += x;
      a0=fmaf(x,blo(v.x),a0); a1=fmaf(x,bhi(v.x),a1); a2=fmaf(x,blo(v.y),a2); a3=fmaf(x,bhi(v.y),a3);
      a4=fmaf(x,blo(v.z),a4); a5=fmaf(x,bhi(v.z),a5); a6=fmaf(x,blo(v.w),a6); a7=fmaf(x,bhi(v.w),a7);
    }
    float inv = 1.f/den;
    a0*=inv; a1*=inv; a2*=inv; a3*=inv; a4*=inv; a5*=inv; a6*=inv; a7*=inv;
  }
  if (OB16){
    uint4 o; o.x = pk2(a0,a1); o.y = pk2(a2,a3); o.z = pk2(a4,a5); o.w = pk2(a6,a7);
    ((uint4*)out)[(size_t)row*16 + lane] = o;
  } else {
    float4* o4 = (float4*)out;
    o4[(size_t)row*32 + lane*2]     = make_float4(a0,a1,a2,a3);
    o4[(size_t)row*32 + lane*2 + 1] = make_float4(a4,a5,a6,a7);
  }
}

template<int OB16>
__device__ __forceinline__ void dev_gcn_gather16(int bid,
    const int* __restrict__ csr, const int* __restrict__ rowp,
    const float* __restrict__ rs, const u16* __restrict__ Y,
    const float* __restrict__ bias, void* __restrict__ out, int n)
{
  int g = threadIdx.x >> 4, lane = threadIdx.x & 15;
  int row = bid*16 + g;
  if (row >= n) return;
  int st = rowp[row], en = rowp[row+1];
  float a0=0,a1=0,a2=0,a3=0,a4=0,a5=0,a6=0,a7=0;
  const uint4* Y8 = (const uint4*)Y;
  int e = st;
  for (; e + 4 <= en; e += 4){
    int s0=csr[e], s1=csr[e+1], s2=csr[e+2], s3=csr[e+3];
    float x0=rs[s0], x1=rs[s1], x2=rs[s2], x3=rs[s3];
    uint4 v0=Y8[(size_t)s0*16+lane], v1=Y8[(size_t)s1*16+lane];
    uint4 v2=Y8[(size_t)s2*16+lane], v3=Y8[(size_t)s3*16+lane];
    a0=fmaf(x0,blo(v0.x),a0); a1=fmaf(x0,bhi(v0.x),a1); a2=fmaf(x0,blo(v0.y),a2); a3=fmaf(x0,bhi(v0.y),a3);
    a4=fmaf(x0,blo(v0.z),a4); a5=fmaf(x0,bhi(v0.z),a5); a6=fmaf(x0,blo(v0.w),a6); a7=fmaf(x0,bhi(v0.w),a7);
    a0=fmaf(x1,blo(v1.x),a0); a1=fmaf(x1,bhi(v1.x),a1); a2=fmaf(x1,blo(v1.y),a2); a3=fmaf(x1,bhi(v1.y),a3);
    a4=fmaf(x1,blo(v1.z),a4); a5=fmaf(x1,bhi(v1.z),a5); a6=fmaf(x1,blo(v1.w),a6); a7=fmaf(x1,bhi(v1.w),a7);
    a0=fmaf(x2,blo(v2.x),a0); a1=fmaf(x2,bhi(v2.x),a1); a2=fmaf(x2,blo(v2.y),a2); a3=fmaf(x2,bhi(v2.y),a3);
    a4=fmaf(x2,blo(v2.z),a4); a5=fmaf(x2,bhi(v2.z),a5); a6=fmaf(x2,blo(v2.w),a6); a7=fmaf(x2,bhi(v2.w),a7);
    a0=fmaf(x3,blo(v3.x),a0); a1=fmaf(x3,bhi(v3.x),a1); a2=fmaf(x3,blo(v3.y),a2); a3=fmaf(x3,bhi(v3.y),a3);
    a4=fmaf(x3,blo(v3.z),a4); a5=fmaf(x3,bhi(v3.z),a5); a6=fmaf(x3,blo(v3.w),a6); a7=fmaf(x3,bhi(v3.w),a7);
  }
  for (; e < en; ++e){
    int sn = csr[e];
    float x = rs[sn];
    uint4 v = Y8[(size_t)sn*16 + lane];
    a0=fmaf(x,blo(v.x),a0); a1=fmaf(x,bhi(v.x),a1); a2=fmaf(x,blo(v.y),a2); a3=fmaf(x,bhi(v.y),a3);
    a4=fmaf(x,blo(v.z),a4); a5=fmaf(x,bhi(v.z),a5); a6=fmaf(x,blo(v.w),a6); a7=fmaf(x,bhi(v.w),a7);
  }
  float sc = rsqrtf(fmaxf((float)(en - st), 1.f));
  const float4* b4 = (const float4*)bias;
  float4 ba = b4[lane*2], bb = b4[lane*2+1];
  float o0=fmaf(a0,sc,ba.x), o1=fmaf(a1,sc,ba.y), o2=fmaf(a2,sc,ba.z), o3=fmaf(a3,sc,ba.w);
  float o4v=fmaf(a4,sc,bb.x), o5=fmaf(a5,sc,bb.y), o6=fmaf(a6,sc,bb.z), o7=fmaf(a7,sc,bb.w);
  if (OB16){
    uint4 o; o.x = pk2(o0,o1); o.y = pk2(o2,o3); o.z = pk2(o4v,o5); o.w = pk2(o6,o7);
    ((uint4*)out)[(size_t)row*16 + lane] = o;
  } else {
    float4* o4 = (float4*)out;
    o4[(size_t)row*32 + lane*2]     = make_float4(o0,o1,o2,o3);
    o4[(size_t)row*32 + lane*2 + 1] = make_float4(o4v,o5,o6,o7);
  }
}

template<int GB16, int DB16>
__device__ __forceinline__ void dev_head(int bid, const void* __restrict__ g, const void* __restrict__ dch,
    const float* __restrict__ W, const float* __restrict__ b,
    float* __restrict__ out, int n, int rowOff)
{
  int wid = threadIdx.x >> 6, lane = threadIdx.x & 63;
  int row = bid*4 + wid;
  if (row >= n) return;
  float x0, x1, x2, x3;
  if (GB16){ const u16* gr = (const u16*)g + (size_t)row*FD; x0 = bf2f(gr[lane]); x1 = bf2f(gr[64+lane]); }
  else     { const float* gr = (const float*)g + (size_t)row*FD; x0 = gr[lane]; x1 = gr[64+lane]; }
  if (DB16){ const u16* dr = (const u16*)dch + (size_t)row*FD; x2 = bf2f(dr[lane]); x3 = bf2f(dr[64+lane]); }
  else     { const float* dr = (const float*)dch + (size_t)row*FD; x2 = dr[lane]; x3 = dr[64+lane]; }
  float acc[5];
  #pragma unroll
  for (int o = 0; o < 5; ++o)
    acc[o] = x0*W[lane*5+o] + x1*W[(64+lane)*5+o] + x2*W[(128+lane)*5+o] + x3*W[(192+lane)*5+o];
  #pragma unroll
  for (int o = 0; o < 5; ++o)
    #pragma unroll
    for (int s = 32; s; s >>= 1) acc[o] += __shfl_xor(acc[o], s);
  if (lane == 0){
    float m = -1e30f;
    #pragma unroll
    for (int o = 0; o < 5; ++o){ acc[o] += b[o]; m = fmaxf(m, acc[o]); }
    float sum = 0.f;
    #pragma unroll
    for (int o = 0; o < 5; ++o){ acc[o] = expf(acc[o]-m); sum += acc[o]; }
    float is = 1.0f/sum;
    float* op = out + (size_t)(rowOff+row)*5;
    #pragma unroll
    for (int o = 0; o < 5; ++o) op[o] = acc[o]*is;
  }
}

// ================= kernels =================

__global__ __launch_bounds__(256) void k1_prep(BMeta m, int* __restrict__ bktCur,
    const float* __restrict__ ekW, const float* __restrict__ ekb, const float* __restrict__ eqb,
    const float* __restrict__ dkW, const float* __restrict__ dkb, const float* __restrict__ dqb,
    float* __restrict__ kv, float inv,
    const float* __restrict__ evW, const float* __restrict__ gW,
    const float* __restrict__ embW, const float* __restrict__ dvW,
    u16* __restrict__ wvt0, u16* __restrict__ wgt0, u16* __restrict__ wvt1, u16* __restrict__ wgt1,
    u16* __restrict__ wembT, u16* __restrict__ wvtd1)
{
  int bid = blockIdx.x;
  if (bid < 4){
    if (threadIdx.x < 128){
      int j = bid;
      const float* kW = (j < 2) ? ekW + j*16384 : dkW + (j-2)*16384;
      const float* kb = (j < 2) ? ekb + j*128   : dkb + (j-2)*128;
      const float* qb = (j < 2) ? eqb + j*128   : dqb + (j-2)*128;
      float* o = kv + j*132;
      int k = threadIdx.x;
      float a = 0.f;
      for (int t = 0; t < 128; ++t) a = fmaf(kW[k*128+t], qb[t], a);
      o[k] = a * inv;
      if (k == 0){
        float c = 0.f;
        for (int t = 0; t < 128; ++t) c = fmaf(kb[t], qb[t], c);
        o[128] = c * inv;
      }
    }
  } else if (bid < 10){
    const float* Ws; u16* Wd;
    if (bid == 4){ Ws = evW;            Wd = wvt0; }
    else if (bid == 5){ Ws = gW;        Wd = wgt0; }
    else if (bid == 6){ Ws = evW+16384; Wd = wvt1; }
    else if (bid == 7){ Ws = gW+16384;  Wd = wgt1; }
    else if (bid == 8){ Ws = embW;      Wd = wembT; }
    else              { Ws = dvW+16384; Wd = wvtd1; }
    for (int i = threadIdx.x; i < 16384; i += 256){
      int k = i >> 7, c = i & 127;
      Wd[c*128 + k] = f2bf(Ws[i]);
    }
  } else {
    for (int i = threadIdx.x; i < 328; i += 256) bktCur[i] = capbase(m, i);
  }
}

// K2: P2 || MFMA h0 gemm (f32 A)
__global__ __launch_bounds__(256) void k2_p2_gemm(BMeta m, int* __restrict__ bktCur,
    u32* __restrict__ ebuf, u16* __restrict__ ebuf16,
    const float* __restrict__ X, const u16* __restrict__ wembT, const float* __restrict__ b,
    u16* __restrict__ bh0, int np2)
{
  __shared__ int sh[4096];
  int bid = blockIdx.x;
  if (bid < np2) dev_p2(m, bid, bktCur, ebuf, ebuf16, sh);
  else dev_single_mfma<1,0>(bid - np2, X, wembT, b, nullptr, nullptr, bh0, N0);
}

// K3: derive counts + per-job exclusive scan (1 block)
__global__ __launch_bounds__(256) void k3_p1(BMeta m, const int* __restrict__ bktCur,
    int* __restrict__ bktCnt, int* __restrict__ bktBase)
{
  __shared__ int sh[384];
  int tid = threadIdx.x;
  for (int i = tid; i < 328; i += 256){
    int cnt = bktCur[i] - capbase(m, i);
    bktCnt[i] = cnt;
    sh[i] = cnt;
  }
  __syncthreads();
  if (tid < 7){
    int acc = 0;
    for (int b = m.boff[tid]; b < m.boff[tid+1]; ++b){ int v = sh[b]; sh[b] = acc; acc += v; }
  }
  __syncthreads();
  for (int i = tid; i < 328; i += 256) bktBase[i] = sh[i];
}

// K4: P3 || MFMA dual(h0) full
__global__ __launch_bounds__(256) void k4_p3_dual(BMeta m,
    const int* __restrict__ bktCnt, const int* __restrict__ bktBase,
    const u32* __restrict__ ebuf, const u16* __restrict__ ebuf16,
    const u16* __restrict__ bh0,
    const u16* __restrict__ wvt0, const u16* __restrict__ wgt0, const float* __restrict__ evb,
    const float* __restrict__ kvec, float* __restrict__ sS, u16* __restrict__ bV, u16* __restrict__ bY0,
    int np3)
{
  __shared__ int sh[1824];
  int bid = blockIdx.x;
  if (bid < np3) dev_p3(m, bid, bktCnt, bktBase, ebuf, ebuf16, sh);
  else dev_dual_mfma(bid - np3, bh0, wvt0, wgt0, evb, kvec, sS, bV, bY0, N0);
}

// K5: attn_gather16(i0)->be1 || g0 slice
__global__ __launch_bounds__(256) void k5_ag_i0(
    const int* __restrict__ csrA, const int* __restrict__ rowpA,
    const float* __restrict__ sS, const u16* __restrict__ bV, u16* __restrict__ be1,
    const int* __restrict__ csr0, const int* __restrict__ rowp0, const float* __restrict__ rs0,
    const u16* __restrict__ bY0, const float* __restrict__ gb, u16* __restrict__ bg0, int nMain, int sBase)
{
  int bid = blockIdx.x;
  if (bid < nMain) dev_attn_gather16<1>(bid, csrA, rowpA, sS, bV, be1, N1);
  else dev_gcn_gather16<1>(sBase + bid - nMain, csr0, rowp0, rs0, bY0, gb, bg0, N0);
}

// K6: MFMA dual(be1 -> V1+score, Y1) || g0 slice
__global__ __launch_bounds__(256) void k6_dual_enc1(
    const u16* __restrict__ be1,
    const u16* __restrict__ wvt1, const u16* __restrict__ wgt1, const float* __restrict__ vb,
    const float* __restrict__ kvec, float* __restrict__ sS, u16* __restrict__ bV, u16* __restrict__ bY1,
    const int* __restrict__ csr0, const int* __restrict__ rowp0, const float* __restrict__ rs0,
    const u16* __restrict__ bY0, const float* __restrict__ gb, u16* __restrict__ bg0, int nMain, int sBase)
{
  int bid = blockIdx.x;
  if (bid < nMain) dev_dual_mfma(bid, be1, wvt1, wgt1, vb, kvec, sS, bV, bY1, N1);
  else dev_gcn_gather16<1>(sBase + bid - nMain, csr0, rowp0, rs0, bY0, gb, bg0, N0);
}

// K7: attn_gather16(i1)->be2(f32) || g0 slice
__global__ __launch_bounds__(256) void k7_ag_i1(
    const int* __restrict__ csrA, const int* __restrict__ rowpA,
    const float* __restrict__ sS, const u16* __restrict__ bV, float* __restrict__ be2,
    const int* __restrict__ csr0, const int* __restrict__ rowp0, const float* __restrict__ rs0,
    const u16* __restrict__ bY0, const float* __restrict__ gb, u16* __restrict__ bg0, int nMain, int sBase)
{
  int bid = blockIdx.x;
  if (bid < nMain) dev_attn_gather16<0>(bid, csrA, rowpA, sS, bV, be2, N2);
  else dev_gcn_gather16<1>(sBase + bid - nMain, csr0, rowp0, rs0, bY0, gb, bg0, N0);
}

// K8: gcn2-Y gemm (f32 A) || gcn_gather16(g1)->bg1 || g0 slice
__global__ __launch_bounds__(256) void k8_y2_g1(
    const float* __restrict__ be2, const float* __restrict__ W2, u16* __restrict__ bY2,
    const int* __restrict__ csr1, const int* __restrict__ rowp1, const float* __restrict__ rs1,
    const u16* __restrict__ bY1, const float* __restrict__ b1, u16* __restrict__ bg1,
    const int* __restrict__ csr0, const int* __restrict__ rowp0, const float* __restrict__ rs0,
    const u16* __restrict__ bY0, const float* __restrict__ gb, u16* __restrict__ bg0,
    int ngemm, int nMain, int sBase)
{
  __shared__ float sm[5120];
  int bid = blockIdx.x;
  if (bid < ngemm) dev_gemm<0,0>(sm, sm+4096, bid, be2, W2, nullptr, nullptr, nullptr, bY2, N2);
  else if (bid < nMain) dev_gcn_gather16<1>(bid - ngemm, csr1, rowp1, rs1, bY1, b1, bg1, N1);
  else dev_gcn_gather16<1>(sBase + bid - nMain, csr0, rowp0, rs0, bY0, gb, bg0, N0);
}

// K9: gcn_gather16(g2)->bg2(f32) || g0 slice
__global__ __launch_bounds__(256) void k9_g2(
    const int* __restrict__ csr2, const int* __restrict__ rowp2, const float* __restrict__ rs2,
    const u16* __restrict__ bY2, const float* __restrict__ b2, float* __restrict__ bg2,
    const int* __restrict__ csr0, const int* __restrict__ rowp0, const float* __restrict__ rs0,
    const u16* __restrict__ bY0, const float* __restrict__ gb, u16* __restrict__ bg0, int nMain, int sBase)
{
  int bid = blockIdx.x;
  if (bid < nMain) dev_gcn_gather16<0>(bid, csr2, rowp2, rs2, bY2, b2, bg2, N2);
  else dev_gcn_gather16<1>(sBase + bid - nMain, csr0, rowp0, rs0, bY0, gb, bg0, N0);
}

// K10: dec0 gemm (f32 A) || head2 || g0 slice
__global__ __launch_bounds__(256) void k10_dec0_head2(
    const float* __restrict__ bg2, const float* __restrict__ vW, const float* __restrict__ vb,
    const float* __restrict__ kvec, float* __restrict__ sS, u16* __restrict__ bV,
    const float* __restrict__ hW, const float* __restrict__ hb, float* __restrict__ out,
    const int* __restrict__ csr0, const int* __restrict__ rowp0, const float* __restrict__ rs0,
    const u16* __restrict__ bY0, const float* __restrict__ gb, u16* __restrict__ bg0,
    int ngemm, int nMain, int sBase)
{
  __shared__ float sm[5120];
  int bid = blockIdx.x;
  if (bid < ngemm) dev_gemm<1,0>(sm, sm+4096, bid, bg2, vW, vb, kvec, sS, bV, N2);
  else if (bid < nMain) dev_head<0,0>(bid - ngemm, bg2, bg2, hW, hb, out, N2, N0+N1);
  else dev_gcn_gather16<1>(sBase + bid - nMain, csr0, rowp0, rs0, bY0, gb, bg0, N0);
}

// K11: attn_gather16(dc0)->be1 (d1) || g0 slice
__global__ __launch_bounds__(256) void k11_ag_d1(
    const int* __restrict__ csrA, const int* __restrict__ rowpA,
    const float* __restrict__ sS, const u16* __restrict__ bV, u16* __restrict__ be1,
    const int* __restrict__ csr0, const int* __restrict__ rowp0, const float* __restrict__ rs0,
    const u16* __restrict__ bY0, const float* __restrict__ gb, u16* __restrict__ bg0, int nMain, int sBase)
{
  int bid = blockIdx.x;
  if (bid < nMain) dev_attn_gather16<1>(bid, csrA, rowpA, sS, bV, be1, N1);
  else dev_gcn_gather16<1>(sBase + bid - nMain, csr0, rowp0, rs0, bY0, gb, bg0, N0);
}

// K12: MFMA dec1 gemm (bf16 A, +score) || head1 || g0 slice
__global__ __launch_bounds__(256) void k12_dec1_head1(
    const u16* __restrict__ be1, const u16* __restrict__ wvtd1, const float* __restrict__ vb,
    const float* __restrict__ kvec, float* __restrict__ sS, u16* __restrict__ bV,
    const u16* __restrict__ bg1, const float* __restrict__ hW, const float* __restrict__ hb,
    float* __restrict__ out,
    const int* __restrict__ csr0, const int* __restrict__ rowp0, const float* __restrict__ rs0,
    const u16* __restrict__ bY0, const float* __restrict__ gb, u16* __restrict__ bg0,
    int ngemm, int nMain, int sBase)
{
  int bid = blockIdx.x;
  if (bid < ngemm) dev_single_mfma<0,1>(bid, be1, wvtd1, vb, kvec, sS, bV, N1);
  else if (bid < nMain) dev_head<1,1>(bid - ngemm, bg1, be1, hW, hb, out, N1, N0);
  else dev_gcn_gather16<1>(sBase + bid - nMain, csr0, rowp0, rs0, bY0, gb, bg0, N0);
}

// K13: fused d0 gather + head0 (16-lane, 4-deep)
__global__ __launch_bounds__(256) void k13_gather_head0(
    const int* __restrict__ csr, const int* __restrict__ rowp,
    const float* __restrict__ w, const u16* __restrict__ V,
    const u16* __restrict__ bg0,
    const float* __restrict__ hW, const float* __restrict__ hb,
    float* __restrict__ out)
{
  int g = threadIdx.x >> 4, lane = threadIdx.x & 15;
  int row = blockIdx.x*16 + g;
  if (row >= N0) return;
  int st = rowp[row], en = rowp[row+1];
  float a0=0,a1=0,a2=0,a3=0,a4=0,a5=0,a6=0,a7=0;
  if (en > st){
    const uint4* V8 = (const uint4*)V;
    float den = 0.f;
    int e = st;
    for (; e + 4 <= en; e += 4){
      int s0=csr[e], s1=csr[e+1], s2=csr[e+2], s3=csr[e+3];
      float x0=w[s0], x1=w[s1], x2=w[s2], x3=w[s3];
      uint4 v0=V8[(size_t)s0*16+lane], v1=V8[(size_t)s1*16+lane];
      uint4 v2=V8[(size_t)s2*16+lane], v3=V8[(size_t)s3*16+lane];
      den += x0+x1+x2+x3;
      a0=fmaf(x0,blo(v0.x),a0); a1=fmaf(x0,bhi(v0.x),a1); a2=fmaf(x0,blo(v0.y),a2); a3=fmaf(x0,bhi(v0.y),a3);
      a4=fmaf(x0,blo(v0.z),a4); a5=fmaf(x0,bhi(v0.z),a5); a6=fmaf(x0,blo(v0.w),a6); a7=fmaf(x0,bhi(v0.w),a7);
      a0=fmaf(x1,blo(v1.x),a0); a1=fmaf(x1,bhi(v1.x),a1); a2=fmaf(x1,blo(v1.y),a2); a3=fmaf(x1,bhi(v1.y),a3);
      a4=fmaf(x1,blo(v1.z),a4); a5=fmaf(x1,bhi(v1.z),a5); a6=fmaf(x1,blo(v1.w),a6); a7=fmaf(x1,bhi(v1.w),a7);
      a0=fmaf(x2,blo(v2.x),a0); a1=fmaf(x2,bhi(v2.x),a1); a2=fmaf(x2,blo(v2.y),a2); a3=fmaf(x2,bhi(v2.y),a3);
      a4=fmaf(x2,blo(v2.z),a4); a5=fmaf(x2,bhi(v2.z),a5); a6=fmaf(x2,blo(v2.w),a6); a7=fmaf(x2,bhi(v2.w),a7);
      a0=fmaf(x3,blo(v3.x),a0); a1=fmaf(x3,bhi(v3.x),a1); a2=fmaf(x3,blo(v3.y),a2); a3=fmaf(x3,bhi(v3.y),a3);
      a4=fmaf(x3,blo(v3.z),a4); a5=fmaf(x3,bhi(v3.z),a5); a6=fmaf(x3,blo(v3.w),a6); a7=fmaf(x3,bhi(v3.w),a7);
    }
    for (; e < en; ++e){
      int sn = csr[e];
      float x = w[sn];
      uint4 v = V8[(size_t)sn*16 + lane];
      den += x;
      a0=fmaf(x,blo(v.x),a0); a1=fmaf(x,bhi(v.x),a1); a2=fmaf(x,blo(v.y),a2); a3=fmaf(x,bhi(v.y),a3);
      a4=fmaf(x,blo(v.z),a4); a5=fmaf(x,bhi(v.z),a5); a6=fmaf(x,blo(v.w),a6); a7=fmaf(x,bhi(v.w),a7);
    }
    float inv = 1.f/den;
    a0*=inv; a1*=inv; a2*=inv; a3*=inv; a4*=inv; a5*=inv; a6*=inv; a7*=inv;
  }
  uint4 gv = ((const uint4*)(bg0 + (size_t)row*FD))[lane];
  float g0 = blo(gv.x), g1 = bhi(gv.x), g2 = blo(gv.y), g3 = bhi(gv.y);
  float g4 = blo(gv.z), g5 = bhi(gv.z), g6 = blo(gv.w), g7 = bhi(gv.w);
  int j = 8*lane;
  float acc[5];
  #pragma unroll
  for (int o = 0; o < 5; ++o){
    acc[o] = g0*hW[(j+0)*5+o] + g1*hW[(j+1)*5+o] + g2*hW[(j+2)*5+o] + g3*hW[(j+3)*5+o]
           + g4*hW[(j+4)*5+o] + g5*hW[(j+5)*5+o] + g6*hW[(j+6)*5+o] + g7*hW[(j+7)*5+o]
           + a0*hW[(128+j+0)*5+o] + a1*hW[(128+j+1)*5+o] + a2*hW[(128+j+2)*5+o] + a3*hW[(128+j+3)*5+o]
           + a4*hW[(128+j+4)*5+o] + a5*hW[(128+j+5)*5+o] + a6*hW[(128+j+6)*5+o] + a7*hW[(128+j+7)*5+o];
  }
  #pragma unroll
  for (int o = 0; o < 5; ++o)
    #pragma unroll
    for (int s = 8; s; s >>= 1) acc[o] += __shfl_xor(acc[o], s, 16);
  if (lane == 0){
    float m = -1e30f;
    #pragma unroll
    for (int o = 0; o < 5; ++o){ acc[o] += hb[o]; m = fmaxf(m, acc[o]); }
    float sum = 0.f;
    #pragma unroll
    for (int o = 0; o < 5; ++o){ acc[o] = expf(acc[o]-m); sum += acc[o]; }
    float is = 1.0f/sum;
    float* op = out + (size_t)row*5;
    #pragma unroll
    for (int o = 0; o < 5; ++o) op[o] = acc[o]*is;
  }
}

// ================= host =================
extern "C" void kernel_launch(void* const* d_in, const int* in_sizes, int n_in,
                              void* d_out, int out_size, void* d_ws, size_t ws_size,
                              hipStream_t stream)
{
  const float* X      = (const float*)d_in[0];
  const float* emb_W  = (const float*)d_in[1];
  const float* emb_b  = (const float*)d_in[2];
  const float* gcn_W  = (const float*)d_in[3];
  const float* gcn_b  = (const float*)d_in[4];
  const float* enc_qb = (const float*)d_in[6];
  const float* enc_kW = (const float*)d_in[7];
  const float* enc_kb = (const float*)d_in[8];
  const float* enc_vW = (const float*)d_in[9];
  const float* enc_vb = (const float*)d_in[10];
  const float* dec_qb = (const float*)d_in[12];
  const float* dec_kW = (const float*)d_in[13];
  const float* dec_kb = (const float*)d_in[14];
  const float* dec_vW = (const float*)d_in[15];
  const float* dec_vb = (const float*)d_in[16];
  const float* head_W = (const float*)d_in[17];
  const float* head_b = (const float*)d_in[18];
  const int* g0s  = (const int*)d_in[19];
  const int* g0d  = (const int*)d_in[20];
  const int* g1s  = (const int*)d_in[21];
  const int* g1d  = (const int*)d_in[22];
  const int* g2s  = (const int*)d_in[23];
  const int* g2d  = (const int*)d_in[24];
  const int* i0s  = (const int*)d_in[25];
  const int* i0d  = (const int*)d_in[26];
  const int* i1s  = (const int*)d_in[27];
  const int* i1d  = (const int*)d_in[28];
  const int* dc0s = (const int*)d_in[29];
  const int* dc0d = (const int*)d_in[30];
  const int* dc1s = (const int*)d_in[31];
  const int* dc1d = (const int*)d_in[32];

  // ---- workspace layout ----
  float* ws = (float*)d_ws;
  float* sS  = ws;                          // N0
  float* kvec = sS + N0;                    // 4*132
  float* be2 = kvec + 4*132;                // N2*FD f32
  float* bg2 = be2 + (size_t)N2*FD;         // N2*FD f32
  float* rs0 = bg2 + (size_t)N2*FD;         // N0
  float* rs1 = rs0 + N0;                    // N1
  float* rs2 = rs1 + N1;                    // N2 (+2 pad)
  u16*  bh0 = (u16*)(rs2 + N2 + 2);         // N0*FD u16
  u16*  be1 = bh0 + (size_t)N0*FD;          // N1*FD u16
  u16*  bg0 = be1 + (size_t)N1*FD;          // N0*FD u16
  u16*  bg1 = bg0 + (size_t)N0*FD;          // N1*FD u16
  u16*  bV  = bg1 + (size_t)N1*FD;          // N0*FD u16 (V tables, time-shared)
  u16*  bY0 = bV  + (size_t)N0*FD;          // N0*FD u16
  u16*  bY1 = bV + 4000000;                 // alias into bV tail
  u16*  bY2 = bV + 8000000;
  int*  bktCnt  = (int*)(bY0 + (size_t)N0*FD);  // 328
  int*  bktBase = bktCnt + 328;                 // 328
  int*  bktCur  = bktBase + 328;                // 328
  int*  rowpBlk = bktCur + 328;                 // 287507
  int*  csrBlk  = rowpBlk + 287507;             // 2,500,000
  u32*  ebuf    = (u32*)(csrBlk + 2500000);     // 2,880,000 u32 (capacity-padded)
  u16*  ebuf16  = (u16*)(ebuf + 2880000);       // 1,712,000 u16
  uintptr_t wtp = ((uintptr_t)(ebuf16 + 1712000) + 15) & ~(uintptr_t)15;
  u16* wvt0 = (u16*)wtp;                        // 16384 each
  u16* wgt0 = wvt0 + 16384;
  u16* wvt1 = wgt0 + 16384;
  u16* wgt1 = wvt1 + 16384;
  u16* wembT = wgt1 + 16384;
  u16* wvtd1 = wembT + 16384;

  const int* keyP[10] = {g0d,g1d,g2d,i0d,i1d,dc0d,dc1d, g0s,g1s,g2s};
  const int* srcP[7]  = {g0s,g1s,g2s,i0s,i1s,dc0s,dc1s};
  const int nArr[10] = {N0,N1,N2,N1,N2,N1,N0, N0,N1,N2};
  const int EArr[10] = {1000000,400000,100000,400000,100000,100000,400000, 1000000,400000,100000};
  const int BArr[10] = {64,32,8,32,8,16,64, 64,32,8};
  const int rArr[10] = {1563,782,782,782,782,1563,1563, 1563,782,782};
  const int capArr[10] = {18000,14000,14000,14000,14000,7600,7600, 18000,14000,14000};

  BMeta m;
  {
    int bo=0, po=0, ro=0, co=0;
    int eb32=0, eb16=0;
    for (int j=0;j<10;++j){
      m.key[j]=keyP[j];
      m.n[j]=nArr[j]; m.E[j]=EArr[j]; m.B[j]=BArr[j]; m.r[j]=rArr[j];
      m.cap[j]=capArr[j];
      m.boff[j]=bo; m.pblk[j]=po;
      bo+=BArr[j]; po+=ceildiv(EArr[j],4096);
      if (j < 7){
        m.src[j]=srcP[j]; m.rowp[j]=rowpBlk+ro; m.csr[j]=csrBlk+co;
        m.ebase[j]=eb32; eb32 += BArr[j]*capArr[j];
        ro+=nArr[j]+1; co+=EArr[j];
      } else {
        m.ebase[j]=eb16; eb16 += BArr[j]*capArr[j];
      }
    }
    m.boff[10]=bo; m.pblk[10]=po;   // 328 / 982
  }
  m.rsout[0]=rs0; m.rsout[1]=rs1; m.rsout[2]=rs2;

  const float invScale = 0.17677669529663687f;
  float* out = (float*)d_out;

  const int NP = m.pblk[10];                // 982
  const int NB = m.boff[10];                // 328
  const int GH0 = ceildiv(N0,32);           // 3125
  const int GH1 = ceildiv(N1,32);           // 782
  const int GH2 = ceildiv(N2,32);           // 196
  const int GA1_16 = ceildiv(N1,16);        // 1563
  const int GA2_16 = ceildiv(N2,16);        // 391
  const int G0B16  = ceildiv(N0,16);        // 6250
  const int GH2H = ceildiv(N2,4);           // 1563
  const int GH1H = ceildiv(N1,4);           // 6250

  int ss[9];
  for (int i = 0; i <= 8; ++i) ss[i] = (int)(((long long)G0B16 * i) / 8);

  // K1: kvec || W transposes || init bktCur
  k1_prep<<<11, 256, 0, stream>>>(m, bktCur,
      enc_kW, enc_kb, enc_qb, dec_kW, dec_kb, dec_qb, kvec, invScale,
      enc_vW, gcn_W, emb_W, dec_vW, wvt0, wgt0, wvt1, wgt1, wembT, wvtd1);
  // K2: P2 || MFMA h0 gemm
  k2_p2_gemm<<<NP + GH0, 256, 0, stream>>>(m, bktCur, ebuf, ebuf16,
      X, wembT, emb_b, bh0, NP);
  // K3: counts + scan
  k3_p1<<<1, 256, 0, stream>>>(m, bktCur, bktCnt, bktBase);
  // K4: P3 || MFMA dual(h0)
  k4_p3_dual<<<NB + GH0, 256, 0, stream>>>(m, bktCnt, bktBase, ebuf, ebuf16,
      bh0, wvt0, wgt0, enc_vb, kvec, sS, bV, bY0, NB);
  // K5: attn_gather(i0)->be1 || g0[0]
  k5_ag_i0<<<GA1_16 + (ss[1]-ss[0]), 256, 0, stream>>>(m.csr[3], m.rowp[3], sS, bV, be1,
      m.csr[0], m.rowp[0], rs0, bY0, gcn_b, bg0, GA1_16, ss[0]);
  // K6: dual(be1 -> V1, Y1) || g0[1]
  k6_dual_enc1<<<GH1 + (ss[2]-ss[1]), 256, 0, stream>>>(be1,
      wvt1, wgt1, enc_vb+128, kvec+132, sS, bV, bY1,
      m.csr[0], m.rowp[0], rs0, bY0, gcn_b, bg0, GH1, ss[1]);
  // K7: attn_gather(i1)->be2 || g0[2]
  k7_ag_i1<<<GA2_16 + (ss[3]-ss[2]), 256, 0, stream>>>(m.csr[4], m.rowp[4], sS, bV, be2,
      m.csr[0], m.rowp[0], rs0, bY0, gcn_b, bg0, GA2_16, ss[2]);
  // K8: gcn2-Y || gather(g1)->bg1 || g0[3]
  k8_y2_g1<<<GH2 + GA1_16 + (ss[4]-ss[3]), 256, 0, stream>>>(be2, gcn_W+32768, bY2,
      m.csr[1], m.rowp[1], rs1, bY1, gcn_b+128, bg1,
      m.csr[0], m.rowp[0], rs0, bY0, gcn_b, bg0, GH2, GH2+GA1_16, ss[3]);
  // K9: gather(g2)->bg2 || g0[4]
  k9_g2<<<GA2_16 + (ss[5]-ss[4]), 256, 0, stream>>>(m.csr[2], m.rowp[2], rs2, bY2, gcn_b+256, bg2,
      m.csr[0], m.rowp[0], rs0, bY0, gcn_b, bg0, GA2_16, ss[4]);
  // K10: dec0 gemm || head2 || g0[5]
  k10_dec0_head2<<<GH2 + GH2H + (ss[6]-ss[5]), 256, 0, stream>>>(bg2, dec_vW, dec_vb, kvec+264, sS, bV,
      head_W+2560, head_b+10, out,
      m.csr[0], m.rowp[0], rs0, bY0, gcn_b, bg0, GH2, GH2+GH2H, ss[5]);
  // K11: attn_gather(dc0)->be1 (d1) || g0[6]
  k11_ag_d1<<<GA1_16 + (ss[7]-ss[6]), 256, 0, stream>>>(m.csr[5], m.rowp[5], sS, bV, be1,
      m.csr[0], m.rowp[0], rs0, bY0, gcn_b, bg0, GA1_16, ss[6]);
  // K12: dec1 gemm || head1 || g0[7]
  k12_dec1_head1<<<GH1 + GH1H + (ss[8]-ss[7]), 256, 0, stream>>>(be1, wvtd1, dec_vb+128, kvec+396, sS, bV,
      bg1, head_W+1280, head_b+5, out,
      m.csr[0], m.rowp[0], rs0, bY0, gcn_b, bg0, GH1, GH1H+GH1, ss[7]);
  // K13: fused d0 gather + head0
  k13_gather_head0<<<G0B16, 256, 0, stream>>>(m.csr[6], m.rowp[6], sS, bV, bg0,
      head_W, head_b, out);
}

// Round 18
// 385.915 us; speedup vs baseline: 1.0099x; 1.0099x over previous
//
#include <hip/hip_runtime.h>
#include <math.h>
#include <stdint.h>

#define N0 100000
#define N1 25000
#define N2 6250
#define FD 128

typedef unsigned short u16;
typedef unsigned int u32;
typedef short bf16x8 __attribute__((ext_vector_type(8)));
typedef float f32x4 __attribute__((ext_vector_type(4)));

static inline int ceildiv(int a, int b){ return (a + b - 1)/b; }

__device__ __forceinline__ u16 f2bf(float f){
  u32 u = __float_as_uint(f);
  u += 0x7fffu + ((u >> 16) & 1u);
  return (u16)(u >> 16);
}
__device__ __forceinline__ float bf2f(u16 h){
  return __uint_as_float(((u32)h) << 16);
}
__device__ __forceinline__ float blo(u32 u){ return __uint_as_float(u << 16); }
__device__ __forceinline__ float bhi(u32 u){ return __uint_as_float(u & 0xffff0000u); }
__device__ __forceinline__ u32 pk2(float a, float b){ return (u32)f2bf(a) | ((u32)f2bf(b) << 16); }

// ================= bucket metadata: 10 jobs =================
struct BMeta {
  const int* key[10];
  const int* src[7];
  int* rowp[7]; int* csr[7];
  float* rsout[3];
  int n[10], E[10], B[10], r[10];
  int cap[10];
  int ebase[10];
  int boff[11];
  int pblk[11];
};

__device__ __forceinline__ int capbase(const BMeta& m, int bb){
  int j = 0;
  #pragma unroll
  for (int t = 1; t < 10; ++t) if (bb >= m.boff[t]) j = t;
  return m.ebase[j] + (bb - m.boff[j]) * m.cap[j];
}

// ================= FMA GEMM (small cases) =================
__device__ __forceinline__ void mm_inner(const float* Al, const float* Wl, int r0, int c0, float acc[4][4]){
  #pragma unroll
  for (int kq = 0; kq < 8; ++kq) {
    int k0 = kq*4;
    float4 a[4], w[4];
    #pragma unroll
    for (int i=0;i<4;++i) a[i] = *(const float4*)&Al[(r0+i)*32 + k0];
    #pragma unroll
    for (int kk=0;kk<4;++kk) w[kk] = *(const float4*)&Wl[(k0+kk)*128 + c0];
    #pragma unroll
    for (int i=0;i<4;++i){
      acc[i][0] = fmaf(a[i].x,w[0].x, fmaf(a[i].y,w[1].x, fmaf(a[i].z,w[2].x, fmaf(a[i].w,w[3].x, acc[i][0]))));
      acc[i][1] = fmaf(a[i].x,w[0].y, fmaf(a[i].y,w[1].y, fmaf(a[i].z,w[2].y, fmaf(a[i].w,w[3].y, acc[i][1]))));
      acc[i][2] = fmaf(a[i].x,w[0].z, fmaf(a[i].y,w[1].z, fmaf(a[i].z,w[2].z, fmaf(a[i].w,w[3].z, acc[i][2]))));
      acc[i][3] = fmaf(a[i].x,w[0].w, fmaf(a[i].y,w[1].w, fmaf(a[i].z,w[2].w, fmaf(a[i].w,w[3].w, acc[i][3]))));
    }
  }
}

template<int SCORE, int AB16>
__device__ __forceinline__ void dev_gemm(float* Wl, float* Al, int bid,
    const void* __restrict__ Ap,
    const float* __restrict__ W, const float* __restrict__ bias,
    const float* __restrict__ kvec, float* __restrict__ sOut,
    u16* __restrict__ out, int n)
{
  const int tid = threadIdx.x;
  const int row0 = bid * 32;
  const int c0 = (tid & 31) * 4, r0 = (tid >> 5) * 4;
  const int r = tid >> 3, fc = tid & 7;
  const int gr_s = row0 + r;
  float acc[4][4] = {};
  float sacc = 0.f;
  const float4* W4 = (const float4*)W;
  for (int kp = 0; kp < 4; ++kp) {
    float4* Wl4 = (float4*)Wl;
    #pragma unroll
    for (int i = 0; i < 4; ++i) Wl4[tid + 256*i] = W4[kp*1024 + tid + 256*i];
    {
      float4 v = make_float4(0.f,0.f,0.f,0.f);
      if (gr_s < n){
        if (AB16){
          ushort4 h = ((const ushort4*)Ap)[(size_t)gr_s*32 + kp*8 + fc];
          v = make_float4(bf2f(h.x), bf2f(h.y), bf2f(h.z), bf2f(h.w));
        } else {
          v = ((const float4*)Ap)[(size_t)gr_s*32 + kp*8 + fc];
        }
      }
      ((float4*)Al)[tid] = v;
      if (SCORE){
        float4 kv = *(const float4*)&kvec[kp*32 + fc*4];
        sacc += v.x*kv.x + v.y*kv.y + v.z*kv.z + v.w*kv.w;
      }
    }
    __syncthreads();
    mm_inner(Al, Wl, r0, c0, acc);
    __syncthreads();
  }
  if (SCORE){
    sacc += __shfl_xor(sacc, 1);
    sacc += __shfl_xor(sacc, 2);
    sacc += __shfl_xor(sacc, 4);
    if (fc == 0 && gr_s < n) sOut[gr_s] = expf(sacc + kvec[128]);
  }
  float4 bv = make_float4(0.f,0.f,0.f,0.f);
  if (bias) bv = *(const float4*)&bias[c0];
  #pragma unroll
  for (int i=0;i<4;++i){
    int gr = row0 + r0 + i;
    if (gr < n){
      ushort4 o;
      o.x = f2bf(acc[i][0]+bv.x); o.y = f2bf(acc[i][1]+bv.y);
      o.z = f2bf(acc[i][2]+bv.z); o.w = f2bf(acc[i][3]+bv.w);
      *(ushort4*)&out[(size_t)gr*FD + c0] = o;
    }
  }
}

// ================= MFMA GEMMs (LDS-free) =================
__device__ __forceinline__ void dev_dual_mfma(int bid,
    const u16* __restrict__ A, const u16* __restrict__ WvT, const u16* __restrict__ WgT,
    const float* __restrict__ vb, const float* __restrict__ kvec, float* __restrict__ sOut,
    u16* __restrict__ Vout, u16* __restrict__ Yout, int n)
{
  const int tid = threadIdx.x;
  const int wid = tid >> 6, lane = tid & 63;
  const int l15 = lane & 15, lg = lane >> 4;
  const int rt = wid & 1;
  const int cbase = (wid >> 1) * 64;
  const int row0 = bid * 32;
  const int arow = row0 + rt*16 + l15;
  const int arowc = min(arow, n-1);
  f32x4 accV[4] = {{0.f,0.f,0.f,0.f},{0.f,0.f,0.f,0.f},{0.f,0.f,0.f,0.f},{0.f,0.f,0.f,0.f}};
  f32x4 accY[4] = {{0.f,0.f,0.f,0.f},{0.f,0.f,0.f,0.f},{0.f,0.f,0.f,0.f},{0.f,0.f,0.f,0.f}};
  float sacc = 0.f;
  #pragma unroll
  for (int ks = 0; ks < 4; ++ks){
    const int ko = ks*32 + lg*8;
    bf16x8 a = *(const bf16x8*)(A + (size_t)arowc*FD + ko);
    if (wid < 2){
      float4 k0 = *(const float4*)(kvec + ko);
      float4 k1 = *(const float4*)(kvec + ko + 4);
      sacc += bf2f((u16)a[0])*k0.x + bf2f((u16)a[1])*k0.y + bf2f((u16)a[2])*k0.z + bf2f((u16)a[3])*k0.w
            + bf2f((u16)a[4])*k1.x + bf2f((u16)a[5])*k1.y + bf2f((u16)a[6])*k1.z + bf2f((u16)a[7])*k1.w;
    }
    #pragma unroll
    for (int ct = 0; ct < 4; ++ct){
      const int col = cbase + ct*16 + l15;
      bf16x8 bv = *(const bf16x8*)(WvT + (size_t)col*FD + ko);
      bf16x8 bg = *(const bf16x8*)(WgT + (size_t)col*FD + ko);
      accV[ct] = __builtin_amdgcn_mfma_f32_16x16x32_bf16(a, bv, accV[ct], 0, 0, 0);
      accY[ct] = __builtin_amdgcn_mfma_f32_16x16x32_bf16(a, bg, accY[ct], 0, 0, 0);
    }
  }
  if (wid < 2){
    sacc += __shfl_xor(sacc, 16);
    sacc += __shfl_xor(sacc, 32);
    if (lane < 16 && arow < n) sOut[arow] = expf(sacc + kvec[128]);
  }
  #pragma unroll
  for (int ct = 0; ct < 4; ++ct){
    const int col = cbase + ct*16 + l15;
    const float bvv = vb[col];
    #pragma unroll
    for (int i = 0; i < 4; ++i){
      int gr = row0 + rt*16 + lg*4 + i;
      if (gr < n){
        Vout[(size_t)gr*FD + col] = f2bf(accV[ct][i] + bvv);
        Yout[(size_t)gr*FD + col] = f2bf(accY[ct][i]);
      }
    }
  }
}

template<int AF32, int SCORE>
__device__ __forceinline__ void dev_single_mfma(int bid,
    const void* __restrict__ Ap, const u16* __restrict__ WT,
    const float* __restrict__ bias,
    const float* __restrict__ kvec, float* __restrict__ sOut,
    u16* __restrict__ out, int n)
{
  const int tid = threadIdx.x;
  const int wid = tid >> 6, lane = tid & 63;
  const int l15 = lane & 15, lg = lane >> 4;
  const int rt = wid & 1;
  const int cbase = (wid >> 1) * 64;
  const int row0 = bid * 32;
  const int arow = row0 + rt*16 + l15;
  const int arowc = min(arow, n-1);
  f32x4 acc[4] = {{0.f,0.f,0.f,0.f},{0.f,0.f,0.f,0.f},{0.f,0.f,0.f,0.f},{0.f,0.f,0.f,0.f}};
  float sacc = 0.f;
  #pragma unroll
  for (int ks = 0; ks < 4; ++ks){
    const int ko = ks*32 + lg*8;
    bf16x8 a;
    if (AF32){
      const float* Af = (const float*)Ap + (size_t)arowc*FD + ko;
      float4 f0 = *(const float4*)Af;
      float4 f1 = *(const float4*)(Af + 4);
      a[0]=(short)f2bf(f0.x); a[1]=(short)f2bf(f0.y); a[2]=(short)f2bf(f0.z); a[3]=(short)f2bf(f0.w);
      a[4]=(short)f2bf(f1.x); a[5]=(short)f2bf(f1.y); a[6]=(short)f2bf(f1.z); a[7]=(short)f2bf(f1.w);
      if (SCORE && wid < 2){
        float4 k0 = *(const float4*)(kvec + ko);
        float4 k1 = *(const float4*)(kvec + ko + 4);
        sacc += f0.x*k0.x + f0.y*k0.y + f0.z*k0.z + f0.w*k0.w
              + f1.x*k1.x + f1.y*k1.y + f1.z*k1.z + f1.w*k1.w;
      }
    } else {
      a = *(const bf16x8*)((const u16*)Ap + (size_t)arowc*FD + ko);
      if (SCORE && wid < 2){
        float4 k0 = *(const float4*)(kvec + ko);
        float4 k1 = *(const float4*)(kvec + ko + 4);
        sacc += bf2f((u16)a[0])*k0.x + bf2f((u16)a[1])*k0.y + bf2f((u16)a[2])*k0.z + bf2f((u16)a[3])*k0.w
              + bf2f((u16)a[4])*k1.x + bf2f((u16)a[5])*k1.y + bf2f((u16)a[6])*k1.z + bf2f((u16)a[7])*k1.w;
      }
    }
    #pragma unroll
    for (int ct = 0; ct < 4; ++ct){
      const int col = cbase + ct*16 + l15;
      bf16x8 bv = *(const bf16x8*)(WT + (size_t)col*FD + ko);
      acc[ct] = __builtin_amdgcn_mfma_f32_16x16x32_bf16(a, bv, acc[ct], 0, 0, 0);
    }
  }
  if (SCORE && wid < 2){
    sacc += __shfl_xor(sacc, 16);
    sacc += __shfl_xor(sacc, 32);
    if (lane < 16 && arow < n) sOut[arow] = expf(sacc + kvec[128]);
  }
  #pragma unroll
  for (int ct = 0; ct < 4; ++ct){
    const int col = cbase + ct*16 + l15;
    const float bvv = bias[col];
    #pragma unroll
    for (int i = 0; i < 4; ++i){
      int gr = row0 + rt*16 + lg*4 + i;
      if (gr < n) out[(size_t)gr*FD + col] = f2bf(acc[ct][i] + bvv);
    }
  }
}

// ================= bucket passes =================
__device__ __forceinline__ int job_of_blk(const BMeta& m, int bid){
  int j = 0;
  #pragma unroll
  for (int t = 1; t < 10; ++t) if (bid >= m.pblk[t]) j = t;
  return j;
}

// P2: per-wave hist + per-wave chunk reservation in capacity-padded buckets.
__device__ __forceinline__ void dev_p2(const BMeta& m, int bid, int* __restrict__ bktCur,
    u32* __restrict__ ebuf, u16* __restrict__ ebuf16, int* sh){
  int j = job_of_blk(m, bid);
  int lb = bid - m.pblk[j];
  const int* key = m.key[j];
  int E = m.E[j], r = m.r[j], B = m.B[j];
  int tid = threadIdx.x, wid = tid >> 6;
  int* wh = sh; int* wstart = sh + 256;
  wh[tid] = 0;
  __syncthreads();
  int base = lb*4096 + tid;
  int* mywh = wh + wid*64;
  #pragma unroll
  for (int i = 0; i < 16; ++i){ int e = base + i*256; if (e < E) atomicAdd(&mywh[key[e]/r], 1); }
  __syncthreads();
  if (tid < B){
    int h0 = wh[tid], h1 = wh[64+tid], h2 = wh[128+tid], h3 = wh[192+tid];
    int g = atomicAdd(&bktCur[m.boff[j] + tid], h0+h1+h2+h3);
    wstart[tid] = g;
    wstart[64+tid] = g + h0;
    wstart[128+tid] = g + h0 + h1;
    wstart[192+tid] = g + h0 + h1 + h2;
  }
  __syncthreads();
  int* myst = wstart + wid*64;
  if (j < 7){
    const int* src = m.src[j];
    #pragma unroll
    for (int i = 0; i < 16; ++i){
      int e = base + i*256;
      if (e < E){
        int s = src[e], d = key[e];
        int b = d / r;
        int pos = atomicAdd(&myst[b], 1);
        ebuf[pos] = ((u32)(d - b*r) << 17) | (u32)s;
      }
    }
  } else {
    #pragma unroll
    for (int i = 0; i < 16; ++i){
      int e = base + i*256;
      if (e < E){
        int k = key[e];
        int b = k / r;
        int pos = atomicAdd(&myst[b], 1);
        ebuf16[pos] = (u16)(k - b*r);
      }
    }
  }
}

__device__ __forceinline__ void dev_p3(const BMeta& m, int bb,
    const int* __restrict__ bktCnt, const int* __restrict__ bktBase,
    const u32* __restrict__ ebuf, const u16* __restrict__ ebuf16, int* sh){
  int j = 0;
  #pragma unroll
  for (int t = 1; t < 10; ++t) if (bb >= m.boff[t]) j = t;
  int b = bb - m.boff[j];
  int n = m.n[j], r = m.r[j];
  int node0 = b*r;
  int rr = min(r, n - node0);
  int gbase = m.ebase[j] + b * m.cap[j];
  int cnt = bktCnt[bb];
  int tid = threadIdx.x;
  if (j >= 7){
    int* hist = sh;
    for (int i = tid; i < rr; i += 256) hist[i] = 0;
    __syncthreads();
    for (int e = tid; e < cnt; e += 256) atomicAdd(&hist[ebuf16[gbase + e]], 1);
    __syncthreads();
    float* rs = m.rsout[j-7];
    for (int i = tid; i < rr; i += 256) rs[node0 + i] = rsqrtf(fmaxf((float)hist[i], 1.f));
    return;
  }
  int B = m.B[j];
  int* rowp = m.rowp[j]; int* csr = m.csr[j];
  int lbase = bktBase[bb];
  int* hist = sh; int* aux = sh + 1568;
  for (int i = tid; i < rr; i += 256) hist[i] = 0;
  __syncthreads();
  for (int e = tid; e < cnt; e += 256){ u32 pk = ebuf[gbase + e]; atomicAdd(&hist[pk >> 17], 1); }
  __syncthreads();
  int ch = (rr + 255) >> 8;
  int i0 = tid*ch;
  int s = 0;
  for (int k = 0; k < ch; ++k){ int idx = i0 + k; if (idx < rr){ int t = hist[idx]; hist[idx] = s; s += t; } }
  aux[tid] = s; __syncthreads();
  for (int off = 1; off < 256; off <<= 1){
    int v = aux[tid]; int a = (tid >= off) ? aux[tid - off] : 0;
    __syncthreads();
    aux[tid] = v + a;
    __syncthreads();
  }
  int pre = (tid ? aux[tid-1] : 0) + lbase;
  for (int k = 0; k < ch; ++k){ int idx = i0 + k; if (idx < rr) hist[idx] += pre; }
  __syncthreads();
  for (int i = tid; i < rr; i += 256) rowp[node0 + i] = hist[i];
  if (b == B-1 && tid == 0) rowp[n] = lbase + cnt;
  __syncthreads();
  for (int e = tid; e < cnt; e += 256){
    u32 pk = ebuf[gbase + e];
    int pos = atomicAdd(&hist[pk >> 17], 1);
    csr[pos] = (int)(pk & 0x1FFFFu);
  }
}

// ================= 16-lane gathers, 4-deep pipelined =================
template<int OB16>
__device__ __forceinline__ void dev_attn_gather16(int bid,
    const int* __restrict__ csr, const int* __restrict__ rowp,
    const float* __restrict__ w, const u16* __restrict__ V,
    void* __restrict__ out, int n)
{
  int g = threadIdx.x >> 4, lane = threadIdx.x & 15;
  int row = bid*16 + g;
  if (row >= n) return;
  int st = rowp[row], en = rowp[row+1];
  float a0=0,a1=0,a2=0,a3=0,a4=0,a5=0,a6=0,a7=0;
  if (en > st){
    const uint4* V8 = (const uint4*)V;
    float den = 0.f;
    int e = st;
    for (; e + 4 <= en; e += 4){
      int s0=csr[e], s1=csr[e+1], s2=csr[e+2], s3=csr[e+3];
      float x0=w[s0], x1=w[s1], x2=w[s2], x3=w[s3];
      uint4 v0=V8[(size_t)s0*16+lane], v1=V8[(size_t)s1*16+lane];
      uint4 v2=V8[(size_t)s2*16+lane], v3=V8[(size_t)s3*16+lane];
      den += x0+x1+x2+x3;
      a0=fmaf(x0,blo(v0.x),a0); a1=fmaf(x0,bhi(v0.x),a1); a2=fmaf(x0,blo(v0.y),a2); a3=fmaf(x0,bhi(v0.y),a3);
      a4=fmaf(x0,blo(v0.z),a4); a5=fmaf(x0,bhi(v0.z),a5); a6=fmaf(x0,blo(v0.w),a6); a7=fmaf(x0,bhi(v0.w),a7);
      a0=fmaf(x1,blo(v1.x),a0); a1=fmaf(x1,bhi(v1.x),a1); a2=fmaf(x1,blo(v1.y),a2); a3=fmaf(x1,bhi(v1.y),a3);
      a4=fmaf(x1,blo(v1.z),a4); a5=fmaf(x1,bhi(v1.z),a5); a6=fmaf(x1,blo(v1.w),a6); a7=fmaf(x1,bhi(v1.w),a7);
      a0=fmaf(x2,blo(v2.x),a0); a1=fmaf(x2,bhi(v2.x),a1); a2=fmaf(x2,blo(v2.y),a2); a3=fmaf(x2,bhi(v2.y),a3);
      a4=fmaf(x2,blo(v2.z),a4); a5=fmaf(x2,bhi(v2.z),a5); a6=fmaf(x2,blo(v2.w),a6); a7=fmaf(x2,bhi(v2.w),a7);
      a0=fmaf(x3,blo(v3.x),a0); a1=fmaf(x3,bhi(v3.x),a1); a2=fmaf(x3,blo(v3.y),a2); a3=fmaf(x3,bhi(v3.y),a3);
      a4=fmaf(x3,blo(v3.z),a4); a5=fmaf(x3,bhi(v3.z),a5); a6=fmaf(x3,blo(v3.w),a6); a7=fmaf(x3,bhi(v3.w),a7);
    }
    for (; e < en; ++e){
      int sn = csr[e];
      float x = w[sn];
      uint4 v = V8[(size_t)sn*16 + lane];
      den += x;
      a0=fmaf(x,blo(v.x),a0); a1=fmaf(x,bhi(v.x),a1); a2=fmaf(x,blo(v.y),a2); a3=fmaf(x,bhi(v.y),a3);
      a4=fmaf(x,blo(v.z),a4); a5=fmaf(x,bhi(v.z),a5); a6=fmaf(x,blo(v.w),a6); a7=fmaf(x,bhi(v.w),a7);
    }
    float inv = 1.f/den;
    a0*=inv; a1*=inv; a2*=inv; a3*=inv; a4*=inv; a5*=inv; a6*=inv; a7*=inv;
  }
  if (OB16){
    uint4 o; o.x = pk2(a0,a1); o.y = pk2(a2,a3); o.z = pk2(a4,a5); o.w = pk2(a6,a7);
    ((uint4*)out)[(size_t)row*16 + lane] = o;
  } else {
    float4* o4 = (float4*)out;
    o4[(size_t)row*32 + lane*2]     = make_float4(a0,a1,a2,a3);
    o4[(size_t)row*32 + lane*2 + 1] = make_float4(a4,a5,a6,a7);
  }
}

template<int OB16>
__device__ __forceinline__ void dev_gcn_gather16(int bid,
    const int* __restrict__ csr, const int* __restrict__ rowp,
    const float* __restrict__ rs, const u16* __restrict__ Y,
    const float* __restrict__ bias, void* __restrict__ out, int n)
{
  int g = threadIdx.x >> 4, lane = threadIdx.x & 15;
  int row = bid*16 + g;
  if (row >= n) return;
  int st = rowp[row], en = rowp[row+1];
  float a0=0,a1=0,a2=0,a3=0,a4=0,a5=0,a6=0,a7=0;
  const uint4* Y8 = (const uint4*)Y;
  int e = st;
  for (; e + 4 <= en; e += 4){
    int s0=csr[e], s1=csr[e+1], s2=csr[e+2], s3=csr[e+3];
    float x0=rs[s0], x1=rs[s1], x2=rs[s2], x3=rs[s3];
    uint4 v0=Y8[(size_t)s0*16+lane], v1=Y8[(size_t)s1*16+lane];
    uint4 v2=Y8[(size_t)s2*16+lane], v3=Y8[(size_t)s3*16+lane];
    a0=fmaf(x0,blo(v0.x),a0); a1=fmaf(x0,bhi(v0.x),a1); a2=fmaf(x0,blo(v0.y),a2); a3=fmaf(x0,bhi(v0.y),a3);
    a4=fmaf(x0,blo(v0.z),a4); a5=fmaf(x0,bhi(v0.z),a5); a6=fmaf(x0,blo(v0.w),a6); a7=fmaf(x0,bhi(v0.w),a7);
    a0=fmaf(x1,blo(v1.x),a0); a1=fmaf(x1,bhi(v1.x),a1); a2=fmaf(x1,blo(v1.y),a2); a3=fmaf(x1,bhi(v1.y),a3);
    a4=fmaf(x1,blo(v1.z),a4); a5=fmaf(x1,bhi(v1.z),a5); a6=fmaf(x1,blo(v1.w),a6); a7=fmaf(x1,bhi(v1.w),a7);
    a0=fmaf(x2,blo(v2.x),a0); a1=fmaf(x2,bhi(v2.x),a1); a2=fmaf(x2,blo(v2.y),a2); a3=fmaf(x2,bhi(v2.y),a3);
    a4=fmaf(x2,blo(v2.z),a4); a5=fmaf(x2,bhi(v2.z),a5); a6=fmaf(x2,blo(v2.w),a6); a7=fmaf(x2,bhi(v2.w),a7);
    a0=fmaf(x3,blo(v3.x),a0); a1=fmaf(x3,bhi(v3.x),a1); a2=fmaf(x3,blo(v3.y),a2); a3=fmaf(x3,bhi(v3.y),a3);
    a4=fmaf(x3,blo(v3.z),a4); a5=fmaf(x3,bhi(v3.z),a5); a6=fmaf(x3,blo(v3.w),a6); a7=fmaf(x3,bhi(v3.w),a7);
  }
  for (; e < en; ++e){
    int sn = csr[e];
    float x = rs[sn];
    uint4 v = Y8[(size_t)sn*16 + lane];
    a0=fmaf(x,blo(v.x),a0); a1=fmaf(x,bhi(v.x),a1); a2=fmaf(x,blo(v.y),a2); a3=fmaf(x,bhi(v.y),a3);
    a4=fmaf(x,blo(v.z),a4); a5=fmaf(x,bhi(v.z),a5); a6=fmaf(x,blo(v.w),a6); a7=fmaf(x,bhi(v.w),a7);
  }
  float sc = rsqrtf(fmaxf((float)(en - st), 1.f));
  const float4* b4 = (const float4*)bias;
  float4 ba = b4[lane*2], bb = b4[lane*2+1];
  float o0=fmaf(a0,sc,ba.x), o1=fmaf(a1,sc,ba.y), o2=fmaf(a2,sc,ba.z), o3=fmaf(a3,sc,ba.w);
  float o4v=fmaf(a4,sc,bb.x), o5=fmaf(a5,sc,bb.y), o6=fmaf(a6,sc,bb.z), o7=fmaf(a7,sc,bb.w);
  if (OB16){
    uint4 o; o.x = pk2(o0,o1); o.y = pk2(o2,o3); o.z = pk2(o4v,o5); o.w = pk2(o6,o7);
    ((uint4*)out)[(size_t)row*16 + lane] = o;
  } else {
    float4* o4 = (float4*)out;
    o4[(size_t)row*32 + lane*2]     = make_float4(o0,o1,o2,o3);
    o4[(size_t)row*32 + lane*2 + 1] = make_float4(o4v,o5,o6,o7);
  }
}

template<int GB16, int DB16>
__device__ __forceinline__ void dev_head(int bid, const void* __restrict__ g, const void* __restrict__ dch,
    const float* __restrict__ W, const float* __restrict__ b,
    float* __restrict__ out, int n, int rowOff)
{
  int wid = threadIdx.x >> 6, lane = threadIdx.x & 63;
  int row = bid*4 + wid;
  if (row >= n) return;
  float x0, x1, x2, x3;
  if (GB16){ const u16* gr = (const u16*)g + (size_t)row*FD; x0 = bf2f(gr[lane]); x1 = bf2f(gr[64+lane]); }
  else     { const float* gr = (const float*)g + (size_t)row*FD; x0 = gr[lane]; x1 = gr[64+lane]; }
  if (DB16){ const u16* dr = (const u16*)dch + (size_t)row*FD; x2 = bf2f(dr[lane]); x3 = bf2f(dr[64+lane]); }
  else     { const float* dr = (const float*)dch + (size_t)row*FD; x2 = dr[lane]; x3 = dr[64+lane]; }
  float acc[5];
  #pragma unroll
  for (int o = 0; o < 5; ++o)
    acc[o] = x0*W[lane*5+o] + x1*W[(64+lane)*5+o] + x2*W[(128+lane)*5+o] + x3*W[(192+lane)*5+o];
  #pragma unroll
  for (int o = 0; o < 5; ++o)
    #pragma unroll
    for (int s = 32; s; s >>= 1) acc[o] += __shfl_xor(acc[o], s);
  if (lane == 0){
    float m = -1e30f;
    #pragma unroll
    for (int o = 0; o < 5; ++o){ acc[o] += b[o]; m = fmaxf(m, acc[o]); }
    float sum = 0.f;
    #pragma unroll
    for (int o = 0; o < 5; ++o){ acc[o] = expf(acc[o]-m); sum += acc[o]; }
    float is = 1.0f/sum;
    float* op = out + (size_t)(rowOff+row)*5;
    #pragma unroll
    for (int o = 0; o < 5; ++o) op[o] = acc[o]*is;
  }
}

// ================= kernels =================

__global__ __launch_bounds__(256) void k1_prep(BMeta m, int* __restrict__ bktCur,
    const float* __restrict__ ekW, const float* __restrict__ ekb, const float* __restrict__ eqb,
    const float* __restrict__ dkW, const float* __restrict__ dkb, const float* __restrict__ dqb,
    float* __restrict__ kv, float inv,
    const float* __restrict__ evW, const float* __restrict__ gW,
    const float* __restrict__ embW, const float* __restrict__ dvW,
    u16* __restrict__ wvt0, u16* __restrict__ wgt0, u16* __restrict__ wvt1, u16* __restrict__ wgt1,
    u16* __restrict__ wembT, u16* __restrict__ wvtd1)
{
  int bid = blockIdx.x;
  if (bid < 4){
    if (threadIdx.x < 128){
      int j = bid;
      const float* kW = (j < 2) ? ekW + j*16384 : dkW + (j-2)*16384;
      const float* kb = (j < 2) ? ekb + j*128   : dkb + (j-2)*128;
      const float* qb = (j < 2) ? eqb + j*128   : dqb + (j-2)*128;
      float* o = kv + j*132;
      int k = threadIdx.x;
      float a = 0.f;
      for (int t = 0; t < 128; ++t) a = fmaf(kW[k*128+t], qb[t], a);
      o[k] = a * inv;
      if (k == 0){
        float c = 0.f;
        for (int t = 0; t < 128; ++t) c = fmaf(kb[t], qb[t], c);
        o[128] = c * inv;
      }
    }
  } else if (bid < 10){
    const float* Ws; u16* Wd;
    if (bid == 4){ Ws = evW;            Wd = wvt0; }
    else if (bid == 5){ Ws = gW;        Wd = wgt0; }
    else if (bid == 6){ Ws = evW+16384; Wd = wvt1; }
    else if (bid == 7){ Ws = gW+16384;  Wd = wgt1; }
    else if (bid == 8){ Ws = embW;      Wd = wembT; }
    else              { Ws = dvW+16384; Wd = wvtd1; }
    for (int i = threadIdx.x; i < 16384; i += 256){
      int k = i >> 7, c = i & 127;
      Wd[c*128 + k] = f2bf(Ws[i]);
    }
  } else {
    for (int i = threadIdx.x; i < 328; i += 256) bktCur[i] = capbase(m, i);
  }
}

// K2: P2 || MFMA h0 gemm (f32 A)
__global__ __launch_bounds__(256) void k2_p2_gemm(BMeta m, int* __restrict__ bktCur,
    u32* __restrict__ ebuf, u16* __restrict__ ebuf16,
    const float* __restrict__ X, const u16* __restrict__ wembT, const float* __restrict__ b,
    u16* __restrict__ bh0, int np2)
{
  __shared__ int sh[512];
  int bid = blockIdx.x;
  if (bid < np2) dev_p2(m, bid, bktCur, ebuf, ebuf16, sh);
  else dev_single_mfma<1,0>(bid - np2, X, wembT, b, nullptr, nullptr, bh0, N0);
}

// K3: derive counts + per-job exclusive scan (1 block)
__global__ __launch_bounds__(256) void k3_p1(BMeta m, const int* __restrict__ bktCur,
    int* __restrict__ bktCnt, int* __restrict__ bktBase)
{
  __shared__ int sh[384];
  int tid = threadIdx.x;
  for (int i = tid; i < 328; i += 256){
    int cnt = bktCur[i] - capbase(m, i);
    bktCnt[i] = cnt;
    sh[i] = cnt;
  }
  __syncthreads();
  if (tid < 7){
    int acc = 0;
    for (int b = m.boff[tid]; b < m.boff[tid+1]; ++b){ int v = sh[b]; sh[b] = acc; acc += v; }
  }
  __syncthreads();
  for (int i = tid; i < 328; i += 256) bktBase[i] = sh[i];
}

// K4: P3 || MFMA dual(h0) full
__global__ __launch_bounds__(256) void k4_p3_dual(BMeta m,
    const int* __restrict__ bktCnt, const int* __restrict__ bktBase,
    const u32* __restrict__ ebuf, const u16* __restrict__ ebuf16,
    const u16* __restrict__ bh0,
    const u16* __restrict__ wvt0, const u16* __restrict__ wgt0, const float* __restrict__ evb,
    const float* __restrict__ kvec, float* __restrict__ sS, u16* __restrict__ bV, u16* __restrict__ bY0,
    int np3)
{
  __shared__ int sh[1824];
  int bid = blockIdx.x;
  if (bid < np3) dev_p3(m, bid, bktCnt, bktBase, ebuf, ebuf16, sh);
  else dev_dual_mfma(bid - np3, bh0, wvt0, wgt0, evb, kvec, sS, bV, bY0, N0);
}

// K5: attn_gather16(i0)->be1 || g0 slice
__global__ __launch_bounds__(256) void k5_ag_i0(
    const int* __restrict__ csrA, const int* __restrict__ rowpA,
    const float* __restrict__ sS, const u16* __restrict__ bV, u16* __restrict__ be1,
    const int* __restrict__ csr0, const int* __restrict__ rowp0, const float* __restrict__ rs0,
    const u16* __restrict__ bY0, const float* __restrict__ gb, u16* __restrict__ bg0, int nMain, int sBase)
{
  int bid = blockIdx.x;
  if (bid < nMain) dev_attn_gather16<1>(bid, csrA, rowpA, sS, bV, be1, N1);
  else dev_gcn_gather16<1>(sBase + bid - nMain, csr0, rowp0, rs0, bY0, gb, bg0, N0);
}

// K6: MFMA dual(be1 -> V1+score, Y1) || g0 slice
__global__ __launch_bounds__(256) void k6_dual_enc1(
    const u16* __restrict__ be1,
    const u16* __restrict__ wvt1, const u16* __restrict__ wgt1, const float* __restrict__ vb,
    const float* __restrict__ kvec, float* __restrict__ sS, u16* __restrict__ bV, u16* __restrict__ bY1,
    const int* __restrict__ csr0, const int* __restrict__ rowp0, const float* __restrict__ rs0,
    const u16* __restrict__ bY0, const float* __restrict__ gb, u16* __restrict__ bg0, int nMain, int sBase)
{
  int bid = blockIdx.x;
  if (bid < nMain) dev_dual_mfma(bid, be1, wvt1, wgt1, vb, kvec, sS, bV, bY1, N1);
  else dev_gcn_gather16<1>(sBase + bid - nMain, csr0, rowp0, rs0, bY0, gb, bg0, N0);
}

// K7: attn_gather16(i1)->be2(f32) || g0 slice
__global__ __launch_bounds__(256) void k7_ag_i1(
    const int* __restrict__ csrA, const int* __restrict__ rowpA,
    const float* __restrict__ sS, const u16* __restrict__ bV, float* __restrict__ be2,
    const int* __restrict__ csr0, const int* __restrict__ rowp0, const float* __restrict__ rs0,
    const u16* __restrict__ bY0, const float* __restrict__ gb, u16* __restrict__ bg0, int nMain, int sBase)
{
  int bid = blockIdx.x;
  if (bid < nMain) dev_attn_gather16<0>(bid, csrA, rowpA, sS, bV, be2, N2);
  else dev_gcn_gather16<1>(sBase + bid - nMain, csr0, rowp0, rs0, bY0, gb, bg0, N0);
}

// K8: gcn2-Y gemm (f32 A) || gcn_gather16(g1)->bg1 || g0 slice
__global__ __launch_bounds__(256) void k8_y2_g1(
    const float* __restrict__ be2, const float* __restrict__ W2, u16* __restrict__ bY2,
    const int* __restrict__ csr1, const int* __restrict__ rowp1, const float* __restrict__ rs1,
    const u16* __restrict__ bY1, const float* __restrict__ b1, u16* __restrict__ bg1,
    const int* __restrict__ csr0, const int* __restrict__ rowp0, const float* __restrict__ rs0,
    const u16* __restrict__ bY0, const float* __restrict__ gb, u16* __restrict__ bg0,
    int ngemm, int nMain, int sBase)
{
  __shared__ float sm[5120];
  int bid = blockIdx.x;
  if (bid < ngemm) dev_gemm<0,0>(sm, sm+4096, bid, be2, W2, nullptr, nullptr, nullptr, bY2, N2);
  else if (bid < nMain) dev_gcn_gather16<1>(bid - ngemm, csr1, rowp1, rs1, bY1, b1, bg1, N1);
  else dev_gcn_gather16<1>(sBase + bid - nMain, csr0, rowp0, rs0, bY0, gb, bg0, N0);
}

// K9: gcn_gather16(g2)->bg2(f32) || g0 slice
__global__ __launch_bounds__(256) void k9_g2(
    const int* __restrict__ csr2, const int* __restrict__ rowp2, const float* __restrict__ rs2,
    const u16* __restrict__ bY2, const float* __restrict__ b2, float* __restrict__ bg2,
    const int* __restrict__ csr0, const int* __restrict__ rowp0, const float* __restrict__ rs0,
    const u16* __restrict__ bY0, const float* __restrict__ gb, u16* __restrict__ bg0, int nMain, int sBase)
{
  int bid = blockIdx.x;
  if (bid < nMain) dev_gcn_gather16<0>(bid, csr2, rowp2, rs2, bY2, b2, bg2, N2);
  else dev_gcn_gather16<1>(sBase + bid - nMain, csr0, rowp0, rs0, bY0, gb, bg0, N0);
}

// K10: dec0 gemm (f32 A) || head2 || g0 slice
__global__ __launch_bounds__(256) void k10_dec0_head2(
    const float* __restrict__ bg2, const float* __restrict__ vW, const float* __restrict__ vb,
    const float* __restrict__ kvec, float* __restrict__ sS, u16* __restrict__ bV,
    const float* __restrict__ hW, const float* __restrict__ hb, float* __restrict__ out,
    const int* __restrict__ csr0, const int* __restrict__ rowp0, const float* __restrict__ rs0,
    const u16* __restrict__ bY0, const float* __restrict__ gb, u16* __restrict__ bg0,
    int ngemm, int nMain, int sBase)
{
  __shared__ float sm[5120];
  int bid = blockIdx.x;
  if (bid < ngemm) dev_gemm<1,0>(sm, sm+4096, bid, bg2, vW, vb, kvec, sS, bV, N2);
  else if (bid < nMain) dev_head<0,0>(bid - ngemm, bg2, bg2, hW, hb, out, N2, N0+N1);
  else dev_gcn_gather16<1>(sBase + bid - nMain, csr0, rowp0, rs0, bY0, gb, bg0, N0);
}

// K11: attn_gather16(dc0)->be1 (d1) || g0 slice
__global__ __launch_bounds__(256) void k11_ag_d1(
    const int* __restrict__ csrA, const int* __restrict__ rowpA,
    const float* __restrict__ sS, const u16* __restrict__ bV, u16* __restrict__ be1,
    const int* __restrict__ csr0, const int* __restrict__ rowp0, const float* __restrict__ rs0,
    const u16* __restrict__ bY0, const float* __restrict__ gb, u16* __restrict__ bg0, int nMain, int sBase)
{
  int bid = blockIdx.x;
  if (bid < nMain) dev_attn_gather16<1>(bid, csrA, rowpA, sS, bV, be1, N1);
  else dev_gcn_gather16<1>(sBase + bid - nMain, csr0, rowp0, rs0, bY0, gb, bg0, N0);
}

// K12: MFMA dec1 gemm (bf16 A, +score) || head1 || g0 slice
__global__ __launch_bounds__(256) void k12_dec1_head1(
    const u16* __restrict__ be1, const u16* __restrict__ wvtd1, const float* __restrict__ vb,
    const float* __restrict__ kvec, float* __restrict__ sS, u16* __restrict__ bV,
    const u16* __restrict__ bg1, const float* __restrict__ hW, const float* __restrict__ hb,
    float* __restrict__ out,
    const int* __restrict__ csr0, const int* __restrict__ rowp0, const float* __restrict__ rs0,
    const u16* __restrict__ bY0, const float* __restrict__ gb, u16* __restrict__ bg0,
    int ngemm, int nMain, int sBase)
{
  int bid = blockIdx.x;
  if (bid < ngemm) dev_single_mfma<0,1>(bid, be1, wvtd1, vb, kvec, sS, bV, N1);
  else if (bid < nMain) dev_head<1,1>(bid - ngemm, bg1, be1, hW, hb, out, N1, N0);
  else dev_gcn_gather16<1>(sBase + bid - nMain, csr0, rowp0, rs0, bY0, gb, bg0, N0);
}

// K13: fused d0 gather + head0 (16-lane, 4-deep)
__global__ __launch_bounds__(256) void k13_gather_head0(
    const int* __restrict__ csr, const int* __restrict__ rowp,
    const float* __restrict__ w, const u16* __restrict__ V,
    const u16* __restrict__ bg0,
    const float* __restrict__ hW, const float* __restrict__ hb,
    float* __restrict__ out)
{
  int g = threadIdx.x >> 4, lane = threadIdx.x & 15;
  int row = blockIdx.x*16 + g;
  if (row >= N0) return;
  int st = rowp[row], en = rowp[row+1];
  float a0=0,a1=0,a2=0,a3=0,a4=0,a5=0,a6=0,a7=0;
  if (en > st){
    const uint4* V8 = (const uint4*)V;
    float den = 0.f;
    int e = st;
    for (; e + 4 <= en; e += 4){
      int s0=csr[e], s1=csr[e+1], s2=csr[e+2], s3=csr[e+3];
      float x0=w[s0], x1=w[s1], x2=w[s2], x3=w[s3];
      uint4 v0=V8[(size_t)s0*16+lane], v1=V8[(size_t)s1*16+lane];
      uint4 v2=V8[(size_t)s2*16+lane], v3=V8[(size_t)s3*16+lane];
      den += x0+x1+x2+x3;
      a0=fmaf(x0,blo(v0.x),a0); a1=fmaf(x0,bhi(v0.x),a1); a2=fmaf(x0,blo(v0.y),a2); a3=fmaf(x0,bhi(v0.y),a3);
      a4=fmaf(x0,blo(v0.z),a4); a5=fmaf(x0,bhi(v0.z),a5); a6=fmaf(x0,blo(v0.w),a6); a7=fmaf(x0,bhi(v0.w),a7);
      a0=fmaf(x1,blo(v1.x),a0); a1=fmaf(x1,bhi(v1.x),a1); a2=fmaf(x1,blo(v1.y),a2); a3=fmaf(x1,bhi(v1.y),a3);
      a4=fmaf(x1,blo(v1.z),a4); a5=fmaf(x1,bhi(v1.z),a5); a6=fmaf(x1,blo(v1.w),a6); a7=fmaf(x1,bhi(v1.w),a7);
      a0=fmaf(x2,blo(v2.x),a0); a1=fmaf(x2,bhi(v2.x),a1); a2=fmaf(x2,blo(v2.y),a2); a3=fmaf(x2,bhi(v2.y),a3);
      a4=fmaf(x2,blo(v2.z),a4); a5=fmaf(x2,bhi(v2.z),a5); a6=fmaf(x2,blo(v2.w),a6); a7=fmaf(x2,bhi(v2.w),a7);
      a0=fmaf(x3,blo(v3.x),a0); a1=fmaf(x3,bhi(v3.x),a1); a2=fmaf(x3,blo(v3.y),a2); a3=fmaf(x3,bhi(v3.y),a3);
      a4=fmaf(x3,blo(v3.z),a4); a5=fmaf(x3,bhi(v3.z),a5); a6=fmaf(x3,blo(v3.w),a6); a7=fmaf(x3,bhi(v3.w),a7);
    }
    for (; e < en; ++e){
      int sn = csr[e];
      float x = w[sn];
      uint4 v = V8[(size_t)sn*16 + lane];
      den += x;
      a0=fmaf(x,blo(v.x),a0); a1=fmaf(x,bhi(v.x),a1); a2=fmaf(x,blo(v.y),a2); a3=fmaf(x,bhi(v.y),a3);
      a4=fmaf(x,blo(v.z),a4); a5=fmaf(x,bhi(v.z),a5); a6=fmaf(x,blo(v.w),a6); a7=fmaf(x,bhi(v.w),a7);
    }
    float inv = 1.f/den;
    a0*=inv; a1*=inv; a2*=inv; a3*=inv; a4*=inv; a5*=inv; a6*=inv; a7*=inv;
  }
  uint4 gv = ((const uint4*)(bg0 + (size_t)row*FD))[lane];
  float g0 = blo(gv.x), g1 = bhi(gv.x), g2 = blo(gv.y), g3 = bhi(gv.y);
  float g4 = blo(gv.z), g5 = bhi(gv.z), g6 = blo(gv.w), g7 = bhi(gv.w);
  int j = 8*lane;
  float acc[5];
  #pragma unroll
  for (int o = 0; o < 5; ++o){
    acc[o] = g0*hW[(j+0)*5+o] + g1*hW[(j+1)*5+o] + g2*hW[(j+2)*5+o] + g3*hW[(j+3)*5+o]
           + g4*hW[(j+4)*5+o] + g5*hW[(j+5)*5+o] + g6*hW[(j+6)*5+o] + g7*hW[(j+7)*5+o]
           + a0*hW[(128+j+0)*5+o] + a1*hW[(128+j+1)*5+o] + a2*hW[(128+j+2)*5+o] + a3*hW[(128+j+3)*5+o]
           + a4*hW[(128+j+4)*5+o] + a5*hW[(128+j+5)*5+o] + a6*hW[(128+j+6)*5+o] + a7*hW[(128+j+7)*5+o];
  }
  #pragma unroll
  for (int o = 0; o < 5; ++o)
    #pragma unroll
    for (int s = 8; s; s >>= 1) acc[o] += __shfl_xor(acc[o], s, 16);
  if (lane == 0){
    float m = -1e30f;
    #pragma unroll
    for (int o = 0; o < 5; ++o){ acc[o] += hb[o]; m = fmaxf(m, acc[o]); }
    float sum = 0.f;
    #pragma unroll
    for (int o = 0; o < 5; ++o){ acc[o] = expf(acc[o]-m); sum += acc[o]; }
    float is = 1.0f/sum;
    float* op = out + (size_t)row*5;
    #pragma unroll
    for (int o = 0; o < 5; ++o) op[o] = acc[o]*is;
  }
}

// ================= host =================
extern "C" void kernel_launch(void* const* d_in, const int* in_sizes, int n_in,
                              void* d_out, int out_size, void* d_ws, size_t ws_size,
                              hipStream_t stream)
{
  const float* X      = (const float*)d_in[0];
  const float* emb_W  = (const float*)d_in[1];
  const float* emb_b  = (const float*)d_in[2];
  const float* gcn_W  = (const float*)d_in[3];
  const float* gcn_b  = (const float*)d_in[4];
  const float* enc_qb = (const float*)d_in[6];
  const float* enc_kW = (const float*)d_in[7];
  const float* enc_kb = (const float*)d_in[8];
  const float* enc_vW = (const float*)d_in[9];
  const float* enc_vb = (const float*)d_in[10];
  const float* dec_qb = (const float*)d_in[12];
  const float* dec_kW = (const float*)d_in[13];
  const float* dec_kb = (const float*)d_in[14];
  const float* dec_vW = (const float*)d_in[15];
  const float* dec_vb = (const float*)d_in[16];
  const float* head_W = (const float*)d_in[17];
  const float* head_b = (const float*)d_in[18];
  const int* g0s  = (const int*)d_in[19];
  const int* g0d  = (const int*)d_in[20];
  const int* g1s  = (const int*)d_in[21];
  const int* g1d  = (const int*)d_in[22];
  const int* g2s  = (const int*)d_in[23];
  const int* g2d  = (const int*)d_in[24];
  const int* i0s  = (const int*)d_in[25];
  const int* i0d  = (const int*)d_in[26];
  const int* i1s  = (const int*)d_in[27];
  const int* i1d  = (const int*)d_in[28];
  const int* dc0s = (const int*)d_in[29];
  const int* dc0d = (const int*)d_in[30];
  const int* dc1s = (const int*)d_in[31];
  const int* dc1d = (const int*)d_in[32];

  // ---- workspace layout ----
  float* ws = (float*)d_ws;
  float* sS  = ws;                          // N0
  float* kvec = sS + N0;                    // 4*132
  float* be2 = kvec + 4*132;                // N2*FD f32
  float* bg2 = be2 + (size_t)N2*FD;         // N2*FD f32
  float* rs0 = bg2 + (size_t)N2*FD;         // N0
  float* rs1 = rs0 + N0;                    // N1
  float* rs2 = rs1 + N1;                    // N2 (+2 pad)
  u16*  bh0 = (u16*)(rs2 + N2 + 2);         // N0*FD u16
  u16*  be1 = bh0 + (size_t)N0*FD;          // N1*FD u16
  u16*  bg0 = be1 + (size_t)N1*FD;          // N0*FD u16
  u16*  bg1 = bg0 + (size_t)N0*FD;          // N1*FD u16
  u16*  bV  = bg1 + (size_t)N1*FD;          // N0*FD u16 (V tables, time-shared)
  u16*  bY0 = bV  + (size_t)N0*FD;          // N0*FD u16
  u16*  bY1 = bV + 4000000;                 // alias into bV tail
  u16*  bY2 = bV + 8000000;
  int*  bktCnt  = (int*)(bY0 + (size_t)N0*FD);  // 328
  int*  bktBase = bktCnt + 328;                 // 328
  int*  bktCur  = bktBase + 328;                // 328
  int*  rowpBlk = bktCur + 328;                 // 287507
  int*  csrBlk  = rowpBlk + 287507;             // 2,500,000
  u32*  ebuf    = (u32*)(csrBlk + 2500000);     // 2,880,000 u32 (capacity-padded)
  u16*  ebuf16  = (u16*)(ebuf + 2880000);       // 1,712,000 u16
  uintptr_t wtp = ((uintptr_t)(ebuf16 + 1712000) + 15) & ~(uintptr_t)15;
  u16* wvt0 = (u16*)wtp;                        // 16384 each
  u16* wgt0 = wvt0 + 16384;
  u16* wvt1 = wgt0 + 16384;
  u16* wgt1 = wvt1 + 16384;
  u16* wembT = wgt1 + 16384;
  u16* wvtd1 = wembT + 16384;

  const int* keyP[10] = {g0d,g1d,g2d,i0d,i1d,dc0d,dc1d, g0s,g1s,g2s};
  const int* srcP[7]  = {g0s,g1s,g2s,i0s,i1s,dc0s,dc1s};
  const int nArr[10] = {N0,N1,N2,N1,N2,N1,N0, N0,N1,N2};
  const int EArr[10] = {1000000,400000,100000,400000,100000,100000,400000, 1000000,400000,100000};
  const int BArr[10] = {64,32,8,32,8,16,64, 64,32,8};
  const int rArr[10] = {1563,782,782,782,782,1563,1563, 1563,782,782};
  const int capArr[10] = {18000,14000,14000,14000,14000,7600,7600, 18000,14000,14000};

  BMeta m;
  {
    int bo=0, po=0, ro=0, co=0;
    int eb32=0, eb16=0;
    for (int j=0;j<10;++j){
      m.key[j]=keyP[j];
      m.n[j]=nArr[j]; m.E[j]=EArr[j]; m.B[j]=BArr[j]; m.r[j]=rArr[j];
      m.cap[j]=capArr[j];
      m.boff[j]=bo; m.pblk[j]=po;
      bo+=BArr[j]; po+=ceildiv(EArr[j],4096);
      if (j < 7){
        m.src[j]=srcP[j]; m.rowp[j]=rowpBlk+ro; m.csr[j]=csrBlk+co;
        m.ebase[j]=eb32; eb32 += BArr[j]*capArr[j];
        ro+=nArr[j]+1; co+=EArr[j];
      } else {
        m.ebase[j]=eb16; eb16 += BArr[j]*capArr[j];
      }
    }
    m.boff[10]=bo; m.pblk[10]=po;   // 328 / 982
  }
  m.rsout[0]=rs0; m.rsout[1]=rs1; m.rsout[2]=rs2;

  const float invScale = 0.17677669529663687f;
  float* out = (float*)d_out;

  const int NP = m.pblk[10];                // 982
  const int NB = m.boff[10];                // 328
  const int GH0 = ceildiv(N0,32);           // 3125
  const int GH1 = ceildiv(N1,32);           // 782
  const int GH2 = ceildiv(N2,32);           // 196
  const int GA1_16 = ceildiv(N1,16);        // 1563
  const int GA2_16 = ceildiv(N2,16);        // 391
  const int G0B16  = ceildiv(N0,16);        // 6250
  const int GH2H = ceildiv(N2,4);           // 1563
  const int GH1H = ceildiv(N1,4);           // 6250

  int ss[9];
  for (int i = 0; i <= 8; ++i) ss[i] = (int)(((long long)G0B16 * i) / 8);

  // K1: kvec || W transposes || init bktCur
  k1_prep<<<11, 256, 0, stream>>>(m, bktCur,
      enc_kW, enc_kb, enc_qb, dec_kW, dec_kb, dec_qb, kvec, invScale,
      enc_vW, gcn_W, emb_W, dec_vW, wvt0, wgt0, wvt1, wgt1, wembT, wvtd1);
  // K2: P2 || MFMA h0 gemm
  k2_p2_gemm<<<NP + GH0, 256, 0, stream>>>(m, bktCur, ebuf, ebuf16,
      X, wembT, emb_b, bh0, NP);
  // K3: counts + scan
  k3_p1<<<1, 256, 0, stream>>>(m, bktCur, bktCnt, bktBase);
  // K4: P3 || MFMA dual(h0)
  k4_p3_dual<<<NB + GH0, 256, 0, stream>>>(m, bktCnt, bktBase, ebuf, ebuf16,
      bh0, wvt0, wgt0, enc_vb, kvec, sS, bV, bY0, NB);
  // K5: attn_gather(i0)->be1 || g0[0]
  k5_ag_i0<<<GA1_16 + (ss[1]-ss[0]), 256, 0, stream>>>(m.csr[3], m.rowp[3], sS, bV, be1,
      m.csr[0], m.rowp[0], rs0, bY0, gcn_b, bg0, GA1_16, ss[0]);
  // K6: dual(be1 -> V1, Y1) || g0[1]
  k6_dual_enc1<<<GH1 + (ss[2]-ss[1]), 256, 0, stream>>>(be1,
      wvt1, wgt1, enc_vb+128, kvec+132, sS, bV, bY1,
      m.csr[0], m.rowp[0], rs0, bY0, gcn_b, bg0, GH1, ss[1]);
  // K7: attn_gather(i1)->be2 || g0[2]
  k7_ag_i1<<<GA2_16 + (ss[3]-ss[2]), 256, 0, stream>>>(m.csr[4], m.rowp[4], sS, bV, be2,
      m.csr[0], m.rowp[0], rs0, bY0, gcn_b, bg0, GA2_16, ss[2]);
  // K8: gcn2-Y || gather(g1)->bg1 || g0[3]
  k8_y2_g1<<<GH2 + GA1_16 + (ss[4]-ss[3]), 256, 0, stream>>>(be2, gcn_W+32768, bY2,
      m.csr[1], m.rowp[1], rs1, bY1, gcn_b+128, bg1,
      m.csr[0], m.rowp[0], rs0, bY0, gcn_b, bg0, GH2, GH2+GA1_16, ss[3]);
  // K9: gather(g2)->bg2 || g0[4]
  k9_g2<<<GA2_16 + (ss[5]-ss[4]), 256, 0, stream>>>(m.csr[2], m.rowp[2], rs2, bY2, gcn_b+256, bg2,
      m.csr[0], m.rowp[0], rs0, bY0, gcn_b, bg0, GA2_16, ss[4]);
  // K10: dec0 gemm || head2 || g0[5]
  k10_dec0_head2<<<GH2 + GH2H + (ss[6]-ss[5]), 256, 0, stream>>>(bg2, dec_vW, dec_vb, kvec+264, sS, bV,
      head_W+2560, head_b+10, out,
      m.csr[0], m.rowp[0], rs0, bY0, gcn_b, bg0, GH2, GH2+GH2H, ss[5]);
  // K11: attn_gather(dc0)->be1 (d1) || g0[6]
  k11_ag_d1<<<GA1_16 + (ss[7]-ss[6]), 256, 0, stream>>>(m.csr[5], m.rowp[5], sS, bV, be1,
      m.csr[0], m.rowp[0], rs0, bY0, gcn_b, bg0, GA1_16, ss[6]);
  // K12: dec1 gemm || head1 || g0[7]
  k12_dec1_head1<<<GH1 + GH1H + (ss[8]-ss[7]), 256, 0, stream>>>(be1, wvtd1, dec_vb+128, kvec+396, sS, bV,
      bg1, head_W+1280, head_b+5, out,
      m.csr[0], m.rowp[0], rs0, bY0, gcn_b, bg0, GH1, GH1+GH1H, ss[7]);
  // K13: fused d0 gather + head0
  k13_gather_head0<<<G0B16, 256, 0, stream>>>(m.csr[6], m.rowp[6], sS, bV, bg0,
      head_W, head_b, out);
}